// Round 8
// baseline (333.585 us; speedup 1.0000x reference)
//
#include <hip/hip_runtime.h>
#include <math.h>

// NeRF renderer: 4096 rays, 128 coarse + 128 fine samples, tiny MLP field.
// One wave (64 lanes) per ray; TWO samples per lane in MLP evals, layer-1
// activations packed f16x2 (64 VGPRs total), layer-2 via v_dot2_f32_f16
// against fp16 W2 rows in LDS (each broadcast row read serves both samples).
//
// Register/spill discipline (R2..R7 lessons, hard-won):
//  1. NEVER index a private array with a non-constant: R6's `unroll 1` on an
//     inner loop made h1a[q] dynamic -> whole array demoted to scratch ->
//     5.9 GB HBM traffic, 45 ms. Every loop touching h1 is fully unrolled.
//  2. __launch_bounds__ min-waves arg sets the VGPR cap = 512/w. (256,2)'s
//     128-cap was BELOW the ~130-160 live set -> pressure spill (R2: 275 MB,
//     R5: 430 MB). Uncapped (R7) the allocator took 236 VGPRs -> only
//     2 waves/SIMD -> latency-bound at VALUBusy 49%. (256,3) caps at 170:
//     above the live set (no spill) but allows 3 waves/SIMD.
//  3. j-loop unroll 1 keeps only 8 f16x8 loads (~32 VGPRs) in flight.

#define BOUNDF 2.0f

typedef _Float16 f16;
typedef f16 f16x2 __attribute__((ext_vector_type(2)));
typedef f16 f16x8 __attribute__((ext_vector_type(8)));

struct RayLds {
    float zc[128];        // coarse z
    float zf[128];        // fine z (sorted by construction)
    float sgc[128];       // coarse sigma
    float sgf[128];       // fine sigma
    float rgbc[128][3];
    float rgbf[128][3];
    float cdf[128];       // 127 used
    float scr[128];       // alphas -> weights scratch
    unsigned short perm[256];
};

__device__ __forceinline__ float sigmoidf(float x) { return 1.0f / (1.0f + __expf(-x)); }

__device__ __forceinline__ float fdot2(f16x2 a, f16x2 b, float c) {
    return __builtin_amdgcn_fdot2(a, b, c, false);   // v_dot2_f32_f16
}

__device__ __forceinline__ float scan_incl_mul(float p, int lane) {
#pragma unroll
    for (int off = 1; off < 64; off <<= 1) {
        float t = __shfl_up(p, off, 64);
        if (lane >= off) p *= t;
    }
    return p;
}

__device__ __forceinline__ float scan_incl_add(float p, int lane) {
#pragma unroll
    for (int off = 1; off < 64; off <<= 1) {
        float t = __shfl_up(p, off, 64);
        if (lane >= off) p += t;
    }
    return p;
}

// MLP field eval for TWO points per lane (A and B). Weights in LDS:
//   sW1t[j] = {W1[0][j], W1[1][j], W1[2][j], b1[j]}           (fp32)
//   sW2h row j (stride 80 halves): [0..63] = W2[:,j] as fp16
//   sHD[j]  = {Wsig[j], Wrgb[j][0], Wrgb[j][1], Wrgb[j][2]}    (fp32)
//   sB2[j]  = b2[j]                                            (fp32)
__device__ __forceinline__ void eval_field2(
    float pxA, float pyA, float pzA, float pxB, float pyB, float pzB,
    const float4* __restrict__ sW1t, const f16* __restrict__ sW2h,
    const float4* __restrict__ sHD, const float* __restrict__ sB2,
    float base_r, float base_g, float base_b,
    float& sgA, float& rA, float& gA, float& bA,
    float& sgB, float& rB, float& gB, float& bB)
{
    // layer 1 (fp32 compute, packed f16x2 store: pair (2j, 2j+1))
    f16x2 h1a[32], h1b[32];
#pragma unroll
    for (int j = 0; j < 32; ++j) {
        float4 w0 = sW1t[2 * j], w1 = sW1t[2 * j + 1];
        float vA0 = fmaxf(fmaf(pxA, w0.x, fmaf(pyA, w0.y, fmaf(pzA, w0.z, w0.w))), 0.0f);
        float vA1 = fmaxf(fmaf(pxA, w1.x, fmaf(pyA, w1.y, fmaf(pzA, w1.z, w1.w))), 0.0f);
        float vB0 = fmaxf(fmaf(pxB, w0.x, fmaf(pyB, w0.y, fmaf(pzB, w0.z, w0.w))), 0.0f);
        float vB1 = fmaxf(fmaf(pxB, w1.x, fmaf(pyB, w1.y, fmaf(pzB, w1.z, w1.w))), 0.0f);
        h1a[j] = f16x2{(f16)vA0, (f16)vA1};
        h1b[j] = f16x2{(f16)vB0, (f16)vB1};
    }

    float asA = 0.f, c0A = 0.f, c1A = 0.f, c2A = 0.f;
    float asB = 0.f, c0B = 0.f, c1B = 0.f, c2B = 0.f;
#pragma unroll 1
    for (int j = 0; j < 64; ++j) {
        const f16* row = sW2h + j * 80;
        float aA0 = sB2[j], aA1 = 0.f, aB0 = 0.f, aB1 = 0.f;  // 2 chains/sample
        // fully unrolled: all h1 indices compile-time constant (R6 lesson)
#pragma unroll
        for (int c = 0; c < 8; ++c) {
            f16x8 w = *(const f16x8*)(row + 8 * c);        // 16B broadcast read
            f16x2 wa = f16x2{w[0], w[1]};
            f16x2 wb = f16x2{w[2], w[3]};
            f16x2 wc = f16x2{w[4], w[5]};
            f16x2 wd = f16x2{w[6], w[7]};
            aA0 = fdot2(h1a[4 * c + 0], wa, aA0);
            aA1 = fdot2(h1a[4 * c + 1], wb, aA1);
            aA0 = fdot2(h1a[4 * c + 2], wc, aA0);
            aA1 = fdot2(h1a[4 * c + 3], wd, aA1);
            aB0 = fdot2(h1b[4 * c + 0], wa, aB0);
            aB1 = fdot2(h1b[4 * c + 1], wb, aB1);
            aB0 = fdot2(h1b[4 * c + 2], wc, aB0);
            aB1 = fdot2(h1b[4 * c + 3], wd, aB1);
        }
        float h2A = fmaxf(aA0 + aA1, 0.0f);
        float h2B = fmaxf(aB0 + aB1, 0.0f);
        float4 hd = sHD[j];   // Wsig, Wrgb0, Wrgb1, Wrgb2
        asA = fmaf(h2A, hd.x, asA); c0A = fmaf(h2A, hd.y, c0A);
        c1A = fmaf(h2A, hd.z, c1A); c2A = fmaf(h2A, hd.w, c2A);
        asB = fmaf(h2B, hd.x, asB); c0B = fmaf(h2B, hd.y, c0B);
        c1B = fmaf(h2B, hd.z, c1B); c2B = fmaf(h2B, hd.w, c2B);
    }
    sgA = fmaxf(asA, 0.0f) + log1pf(__expf(-fabsf(asA)));   // stable softplus
    sgB = fmaxf(asB, 0.0f) + log1pf(__expf(-fabsf(asB)));
    rA = sigmoidf(c0A + base_r); gA = sigmoidf(c1A + base_g); bA = sigmoidf(c2A + base_b);
    rB = sigmoidf(c0B + base_r); gB = sigmoidf(c1B + base_g); bB = sigmoidf(c2B + base_b);
}

__global__ __launch_bounds__(256, 3)
void nerf_kernel(const float* __restrict__ rays_o, const float* __restrict__ rays_d,
                 const float* __restrict__ W1, const float* __restrict__ b1,
                 const float* __restrict__ W2, const float* __restrict__ b2,
                 const float* __restrict__ Wsig, const float* __restrict__ Wrgb,
                 const float* __restrict__ brgb,
                 float* __restrict__ out_depth, float* __restrict__ out_img,
                 int nRays)
{
    __shared__ __align__(16) float4 sW1t[64];
    __shared__ __align__(16) f16 sW2h[64 * 80];
    __shared__ __align__(16) float4 sHD[64];
    __shared__ float sB2[64];
    __shared__ RayLds rl[4];

    const int tid  = threadIdx.x;
    const int lane = tid & 63;
    const int wv   = tid >> 6;

    // --- stage weights (whole block) ---
    if (tid < 64) {
        sW1t[tid] = make_float4(W1[tid], W1[64 + tid], W1[128 + tid], b1[tid]);
        sHD[tid]  = make_float4(Wsig[tid], Wrgb[tid * 3 + 0], Wrgb[tid * 3 + 1], Wrgb[tid * 3 + 2]);
        sB2[tid]  = b2[tid];
    }
    for (int idx = tid; idx < 4096; idx += 256) {
        int i = idx >> 6, j = idx & 63;
        sW2h[j * 80 + i] = (f16)W2[i * 64 + j];   // transposed, fp16
    }
    __syncthreads();

    int ray = blockIdx.x * 4 + wv;
    bool valid = ray < nRays;
    int rayc = valid ? ray : (nRays - 1);
    RayLds& R = rl[wv];

    const float ox = rays_o[rayc * 3 + 0], oy = rays_o[rayc * 3 + 1], oz = rays_o[rayc * 3 + 2];
    const float dx = rays_d[rayc * 3 + 0], dy = rays_d[rayc * 3 + 1], dzv = rays_d[rayc * 3 + 2];

    // --- near/far vs cube [-2,2]^3 ---
    float t0x = (-BOUNDF - ox) / (dx + 1e-15f), t1x = (BOUNDF - ox) / (dx + 1e-15f);
    float t0y = (-BOUNDF - oy) / (dy + 1e-15f), t1y = (BOUNDF - oy) / (dy + 1e-15f);
    float t0z = (-BOUNDF - oz) / (dzv + 1e-15f), t1z = (BOUNDF - oz) / (dzv + 1e-15f);
    float nearv = fmaxf(fminf(t0x, t1x), fmaxf(fminf(t0y, t1y), fminf(t0z, t1z)));
    float farv  = fminf(fmaxf(t0x, t1x), fminf(fmaxf(t0y, t1y), fmaxf(t0z, t1z)));
    if (farv < nearv) { nearv = 1e9f; farv = 1e9f; }
    nearv = fmaxf(nearv, 0.05f);
    const float span = farv - nearv;
    const float dzc = span * (1.0f / 127.0f);
    const float sample_dist = span * (1.0f / 128.0f);

    // per-ray rgb bias: brgb + dirs @ Wrgb[64:67]
    const float base_r = brgb[0] + dx * Wrgb[64 * 3 + 0] + dy * Wrgb[65 * 3 + 0] + dzv * Wrgb[66 * 3 + 0];
    const float base_g = brgb[1] + dx * Wrgb[64 * 3 + 1] + dy * Wrgb[65 * 3 + 1] + dzv * Wrgb[66 * 3 + 1];
    const float base_b = brgb[2] + dx * Wrgb[64 * 3 + 2] + dy * Wrgb[65 * 3 + 2] + dzv * Wrgb[66 * 3 + 2];

    const int s0 = lane, s1 = lane + 64;

    // --- coarse eval: samples s0 (A) and s1 (B) per lane ---
    {
        float zA = fmaf(span, (float)s0 * (1.0f / 127.0f), nearv);
        float zB = fmaf(span, (float)s1 * (1.0f / 127.0f), nearv);
        R.zc[s0] = zA; R.zc[s1] = zB;
        float pxA = fminf(fmaxf(fmaf(dx, zA, ox), -BOUNDF), BOUNDF);
        float pyA = fminf(fmaxf(fmaf(dy, zA, oy), -BOUNDF), BOUNDF);
        float pzA = fminf(fmaxf(fmaf(dzv, zA, oz), -BOUNDF), BOUNDF);
        float pxB = fminf(fmaxf(fmaf(dx, zB, ox), -BOUNDF), BOUNDF);
        float pyB = fminf(fmaxf(fmaf(dy, zB, oy), -BOUNDF), BOUNDF);
        float pzB = fminf(fmaxf(fmaf(dzv, zB, oz), -BOUNDF), BOUNDF);
        float sgA, rA, gA, bA, sgB, rB, gB, bB;
        eval_field2(pxA, pyA, pzA, pxB, pyB, pzB, sW1t, sW2h, sHD, sB2,
                    base_r, base_g, base_b, sgA, rA, gA, bA, sgB, rB, gB, bB);
        R.sgc[s0] = sgA; R.rgbc[s0][0] = rA; R.rgbc[s0][1] = gA; R.rgbc[s0][2] = bA;
        R.sgc[s1] = sgB; R.rgbc[s1][0] = rB; R.rgbc[s1][1] = gB; R.rgbc[s1][2] = bB;

        // coarse alphas (deltas from actual z, matching reference)
        float znA = R.zc[s0 + 1];
        int   snB = (s1 < 127) ? s1 + 1 : 127;
        float znB = R.zc[snB];
        float dA = znA - zA;
        float dB = (s1 < 127) ? (znB - zB) : sample_dist;
        R.scr[s0] = 1.0f - __expf(-dA * sgA);
        R.scr[s1] = 1.0f - __expf(-dB * sgB);
    }

    // --- wave-parallel cumprod: weights for elements 2l, 2l+1 ---
    {
        float aa = R.scr[2 * lane], ab = R.scr[2 * lane + 1];
        float ma = 1.0f - aa + 1e-15f, mb = 1.0f - ab + 1e-15f;
        float p = scan_incl_mul(ma * mb, lane);
        float T0 = __shfl_up(p, 1, 64);
        if (lane == 0) T0 = 1.0f;
        R.scr[2 * lane]     = aa * T0;
        R.scr[2 * lane + 1] = ab * (T0 * ma);
    }

    // --- wave-parallel CDF over pdf[m]=w[1+m]+1e-5, m=0..125 ---
    {
        float pA = 0.f, pB = 0.f;
        if (lane < 63) {
            pA = R.scr[2 * lane + 1] + 1e-5f;
            pB = R.scr[2 * lane + 2] + 1e-5f;
        }
        float S = scan_incl_add(pA + pB, lane);
        float total = __shfl(S, 63, 64);
        float sexcl = __shfl_up(S, 1, 64);
        if (lane == 0) sexcl = 0.f;
        float inv = 1.0f / total;
        if (lane == 63) {
            R.cdf[0] = 0.0f;
        } else {
            R.cdf[1 + 2 * lane] = (sexcl + pA) * inv;
            R.cdf[2 + 2 * lane] = (sexcl + pA + pB) * inv;
        }
    }

    // --- inverse-CDF sampling: i0=lane, i1=lane+64 ---
#pragma unroll
    for (int bt = 0; bt < 2; ++bt) {
        int i = bt * 64 + lane;
        float u = (float)(2 * i + 1) * (1.0f / 256.0f);
        int lo = 0, hi = 127;   // searchsorted right over cdf[0..126]
        while (lo < hi) { int mid = (lo + hi) >> 1; if (R.cdf[mid] <= u) lo = mid + 1; else hi = mid; }
        int below = max(lo - 1, 0), above = min(lo, 126);
        float cb = R.cdf[below], ca = R.cdf[above];
        float binb = fmaf(dzc, (float)below + 0.5f, nearv);
        float bina = fmaf(dzc, (float)above + 0.5f, nearv);
        float denom = ca - cb;
        if (denom < 1e-5f) denom = 1.0f;
        float t = (u - cb) / denom;
        R.zf[i] = fmaf(t, bina - binb, binb);
    }

    // --- fine eval: samples s0 (A) and s1 (B) per lane ---
    {
        float zA = R.zf[s0], zB = R.zf[s1];
        float pxA = fminf(fmaxf(fmaf(dx, zA, ox), -BOUNDF), BOUNDF);
        float pyA = fminf(fmaxf(fmaf(dy, zA, oy), -BOUNDF), BOUNDF);
        float pzA = fminf(fmaxf(fmaf(dzv, zA, oz), -BOUNDF), BOUNDF);
        float pxB = fminf(fmaxf(fmaf(dx, zB, ox), -BOUNDF), BOUNDF);
        float pyB = fminf(fmaxf(fmaf(dy, zB, oy), -BOUNDF), BOUNDF);
        float pzB = fminf(fmaxf(fmaf(dzv, zB, oz), -BOUNDF), BOUNDF);
        float sgA, rA, gA, bA, sgB, rB, gB, bB;
        eval_field2(pxA, pyA, pzA, pxB, pyB, pzB, sW1t, sW2h, sHD, sB2,
                    base_r, base_g, base_b, sgA, rA, gA, bA, sgB, rB, gB, bB);
        R.sgf[s0] = sgA; R.rgbf[s0][0] = rA; R.rgbf[s0][1] = gA; R.rgbf[s0][2] = bA;
        R.sgf[s1] = sgB; R.rgbf[s1][0] = rB; R.rgbf[s1][1] = gB; R.rgbf[s1][2] = bB;
    }

    // --- stable merge of two sorted length-128 lists (merge-path ranks) ---
#pragma unroll
    for (int bt = 0; bt < 2; ++bt) {
        int k = bt * 64 + lane;
        float v = R.zc[k];
        int lo = 0, hi = 128;
        while (lo < hi) { int mid = (lo + hi) >> 1; if (R.zf[mid] < v) lo = mid + 1; else hi = mid; }
        R.perm[k + lo] = (unsigned short)k;
        float vf = R.zf[k];
        lo = 0; hi = 128;
        while (lo < hi) { int mid = (lo + hi) >> 1; if (R.zc[mid] <= vf) lo = mid + 1; else hi = mid; }
        R.perm[k + lo] = (unsigned short)(128 + k);
    }

    // --- merged composite: 4 samples per lane, scan + accumulate in regs ---
    {
        int sb = 4 * lane;
        int idxk[4]; float zk[4], sgk[4];
#pragma unroll
        for (int k = 0; k < 4; ++k) {
            int idx = R.perm[sb + k];
            idxk[k] = idx;
            zk[k]  = (idx < 128) ? R.zc[idx]  : R.zf[idx - 128];
            sgk[k] = (idx < 128) ? R.sgc[idx] : R.sgf[idx - 128];
        }
        float znext = __shfl_down(zk[0], 1, 64);   // z of sample 4l+4
        float d0 = zk[1] - zk[0];
        float d1 = zk[2] - zk[1];
        float d2 = zk[3] - zk[2];
        float d3 = (lane < 63) ? (znext - zk[3]) : sample_dist;
        float a0 = 1.0f - __expf(-d0 * sgk[0]);
        float a1 = 1.0f - __expf(-d1 * sgk[1]);
        float a2 = 1.0f - __expf(-d2 * sgk[2]);
        float a3 = 1.0f - __expf(-d3 * sgk[3]);
        float m0 = 1.0f - a0 + 1e-15f, m1 = 1.0f - a1 + 1e-15f;
        float m2 = 1.0f - a2 + 1e-15f, m3 = 1.0f - a3 + 1e-15f;
        float p = scan_incl_mul((m0 * m1) * (m2 * m3), lane);
        float T = __shfl_up(p, 1, 64);
        if (lane == 0) T = 1.0f;

        const float invspan = 1.0f / span;  // span==0 -> inf; 0*inf = NaN (matches jnp)
        float dacc = 0.f, racc = 0.f, gacc = 0.f, bacc = 0.f, wacc = 0.f;
        float aarr[4] = {a0, a1, a2, a3};
        float marr[4] = {m0, m1, m2, m3};
#pragma unroll
        for (int k = 0; k < 4; ++k) {
            float w = aarr[k] * T;
            float ozv = (zk[k] - nearv) * invspan;
            ozv = (ozv < 0.0f) ? 0.0f : ((ozv > 1.0f) ? 1.0f : ozv);  // NaN propagates
            dacc = fmaf(w, ozv, dacc);
            const float* rgb = (idxk[k] < 128) ? R.rgbc[idxk[k]] : R.rgbf[idxk[k] - 128];
            racc = fmaf(w, rgb[0], racc);
            gacc = fmaf(w, rgb[1], gacc);
            bacc = fmaf(w, rgb[2], bacc);
            wacc += w;
            T *= marr[k];
        }
#pragma unroll
        for (int off = 32; off; off >>= 1) {
            dacc += __shfl_xor(dacc, off);
            racc += __shfl_xor(racc, off);
            gacc += __shfl_xor(gacc, off);
            bacc += __shfl_xor(bacc, off);
            wacc += __shfl_xor(wacc, off);
        }
        if (lane == 0 && valid) {
            out_depth[ray] = dacc;
            float bg = 1.0f - wacc;
            out_img[ray * 3 + 0] = racc + bg;
            out_img[ray * 3 + 1] = gacc + bg;
            out_img[ray * 3 + 2] = bacc + bg;
        }
    }
}

extern "C" void kernel_launch(void* const* d_in, const int* in_sizes, int n_in,
                              void* d_out, int out_size, void* d_ws, size_t ws_size,
                              hipStream_t stream) {
    const float* rays_o = (const float*)d_in[0];
    const float* rays_d = (const float*)d_in[1];
    const float* W1   = (const float*)d_in[2];
    const float* b1   = (const float*)d_in[3];
    const float* W2   = (const float*)d_in[4];
    const float* b2   = (const float*)d_in[5];
    const float* Wsig = (const float*)d_in[6];
    const float* Wrgb = (const float*)d_in[7];
    const float* brgb = (const float*)d_in[8];

    int N = in_sizes[0] / 3;          // 4096 rays
    float* out = (float*)d_out;
    float* out_depth = out;           // [N]
    float* out_img   = out + N;       // [N,3]

    int blocks = (N + 3) / 4;
    nerf_kernel<<<dim3(blocks), dim3(256), 0, stream>>>(
        rays_o, rays_d, W1, b1, W2, b2, Wsig, Wrgb, brgb,
        out_depth, out_img, N);
}

// Round 9
// 256.322 us; speedup vs baseline: 1.3014x; 1.3014x over previous
//
#include <hip/hip_runtime.h>
#include <math.h>

// NeRF renderer: 4096 rays, 128 coarse + 128 fine samples, tiny MLP field.
// One wave (64 lanes) per ray; TWO samples per lane in MLP evals, layer-1
// activations packed f16x2 (64 VGPRs total), layer-2 via v_dot2_f32_f16.
// W2 weights are WAVE-UNIFORM -> read from global memory (prep-packed fp16 in
// d_ws) with uniform indices so the compiler emits scalar s_load into SGPRs;
// fdot2 consumes the weight as its single allowed scalar operand. This removes
// ~1000 ds_read_b128/ray (the R7 latency bottleneck) and ~32 VGPRs of
// in-flight weight loads.
//
// Register/spill discipline (R2..R8 lessons, hard-won):
//  1. NEVER index a private array with a non-constant (R6: h1 demoted to
//     scratch -> 5.9 GB HBM, 45 ms). Loops touching h1 are fully unrolled.
//  2. NEVER use the __launch_bounds__ min-waves arg: (256,2) capped VGPR at
//     128 -> spill (R2/R5: 275-430 MB); (256,3) allocated 84 (!) -> 624 MB
//     spill (R8). Plain (256) is the only reliable config.
//  3. hbm_bytes is the spill detector: clean runs show <2 MB.

#define BOUNDF 2.0f

typedef _Float16 f16;
typedef f16 f16x2 __attribute__((ext_vector_type(2)));

struct RayLds {
    float zc[128];        // coarse z
    float zf[128];        // fine z (sorted by construction)
    float sgc[128];       // coarse sigma
    float sgf[128];       // fine sigma
    float rgbc[128][3];
    float rgbf[128][3];
    float cdf[128];       // 127 used
    float scr[128];       // alphas -> weights scratch
    unsigned short perm[256];
};

__device__ __forceinline__ float sigmoidf(float x) { return 1.0f / (1.0f + __expf(-x)); }

__device__ __forceinline__ float fdot2(f16x2 a, f16x2 b, float c) {
    return __builtin_amdgcn_fdot2(a, b, c, false);   // v_dot2_f32_f16
}

__device__ __forceinline__ f16x2 asf16x2(unsigned int u) {
    return __builtin_bit_cast(f16x2, u);
}

__device__ __forceinline__ float scan_incl_mul(float p, int lane) {
#pragma unroll
    for (int off = 1; off < 64; off <<= 1) {
        float t = __shfl_up(p, off, 64);
        if (lane >= off) p *= t;
    }
    return p;
}

__device__ __forceinline__ float scan_incl_add(float p, int lane) {
#pragma unroll
    for (int off = 1; off < 64; off <<= 1) {
        float t = __shfl_up(p, off, 64);
        if (lane >= off) p += t;
    }
    return p;
}

// Prep: pack W2 transposed as fp16 pairs. wq[j*32 + c] = {W2[2c][j], W2[2c+1][j]}
__global__ __launch_bounds__(256)
void prep_w2(const float* __restrict__ W2, unsigned int* __restrict__ wq) {
    int tid = blockIdx.x * 256 + threadIdx.x;
    if (tid < 2048) {
        int j = tid >> 5, c = tid & 31;
        f16x2 p;
        p[0] = (f16)W2[(2 * c) * 64 + j];
        p[1] = (f16)W2[(2 * c + 1) * 64 + j];
        wq[tid] = __builtin_bit_cast(unsigned int, p);
    }
}

// MLP field eval for TWO points per lane (A and B).
//   sW1t[j] = {W1[0][j], W1[1][j], W1[2][j], b1[j]}  (LDS, fp32, broadcast)
//   wq      = packed fp16 W2 rows in GLOBAL memory, uniform-indexed -> s_load
//   sHD[j]  = {Wsig[j], Wrgb[j][0..2]} (LDS fp32);  sB2[j] = b2[j]
__device__ __forceinline__ void eval_field2(
    float pxA, float pyA, float pzA, float pxB, float pyB, float pzB,
    const float4* __restrict__ sW1t, const unsigned int* __restrict__ wq,
    const float4* __restrict__ sHD, const float* __restrict__ sB2,
    float base_r, float base_g, float base_b,
    float& sgA, float& rA, float& gA, float& bA,
    float& sgB, float& rB, float& gB, float& bB)
{
    // layer 1 (fp32 compute, packed f16x2 store: pair (2j, 2j+1))
    f16x2 h1a[32], h1b[32];
#pragma unroll
    for (int j = 0; j < 32; ++j) {
        float4 w0 = sW1t[2 * j], w1 = sW1t[2 * j + 1];
        float vA0 = fmaxf(fmaf(pxA, w0.x, fmaf(pyA, w0.y, fmaf(pzA, w0.z, w0.w))), 0.0f);
        float vA1 = fmaxf(fmaf(pxA, w1.x, fmaf(pyA, w1.y, fmaf(pzA, w1.z, w1.w))), 0.0f);
        float vB0 = fmaxf(fmaf(pxB, w0.x, fmaf(pyB, w0.y, fmaf(pzB, w0.z, w0.w))), 0.0f);
        float vB1 = fmaxf(fmaf(pxB, w1.x, fmaf(pyB, w1.y, fmaf(pzB, w1.z, w1.w))), 0.0f);
        h1a[j] = f16x2{(f16)vA0, (f16)vA1};
        h1b[j] = f16x2{(f16)vB0, (f16)vB1};
    }

    float asA = 0.f, c0A = 0.f, c1A = 0.f, c2A = 0.f;
    float asB = 0.f, c0B = 0.f, c1B = 0.f, c2B = 0.f;
#pragma unroll 1
    for (int j = 0; j < 64; ++j) {
        const unsigned int* row = wq + j * 32;   // uniform address -> s_load
        float aA0 = sB2[j], aA1 = 0.f, aB0 = 0.f, aB1 = 0.f;  // 2 chains/sample
        // fully unrolled: all h1 indices compile-time constant (R6 lesson)
#pragma unroll
        for (int c = 0; c < 8; ++c) {
            f16x2 w0 = asf16x2(row[4 * c + 0]);
            f16x2 w1 = asf16x2(row[4 * c + 1]);
            f16x2 w2 = asf16x2(row[4 * c + 2]);
            f16x2 w3 = asf16x2(row[4 * c + 3]);
            aA0 = fdot2(h1a[4 * c + 0], w0, aA0);
            aA1 = fdot2(h1a[4 * c + 1], w1, aA1);
            aA0 = fdot2(h1a[4 * c + 2], w2, aA0);
            aA1 = fdot2(h1a[4 * c + 3], w3, aA1);
            aB0 = fdot2(h1b[4 * c + 0], w0, aB0);
            aB1 = fdot2(h1b[4 * c + 1], w1, aB1);
            aB0 = fdot2(h1b[4 * c + 2], w2, aB0);
            aB1 = fdot2(h1b[4 * c + 3], w3, aB1);
        }
        float h2A = fmaxf(aA0 + aA1, 0.0f);
        float h2B = fmaxf(aB0 + aB1, 0.0f);
        float4 hd = sHD[j];   // Wsig, Wrgb0, Wrgb1, Wrgb2
        asA = fmaf(h2A, hd.x, asA); c0A = fmaf(h2A, hd.y, c0A);
        c1A = fmaf(h2A, hd.z, c1A); c2A = fmaf(h2A, hd.w, c2A);
        asB = fmaf(h2B, hd.x, asB); c0B = fmaf(h2B, hd.y, c0B);
        c1B = fmaf(h2B, hd.z, c1B); c2B = fmaf(h2B, hd.w, c2B);
    }
    sgA = fmaxf(asA, 0.0f) + log1pf(__expf(-fabsf(asA)));   // stable softplus
    sgB = fmaxf(asB, 0.0f) + log1pf(__expf(-fabsf(asB)));
    rA = sigmoidf(c0A + base_r); gA = sigmoidf(c1A + base_g); bA = sigmoidf(c2A + base_b);
    rB = sigmoidf(c0B + base_r); gB = sigmoidf(c1B + base_g); bB = sigmoidf(c2B + base_b);
}

__global__ __launch_bounds__(256)
void nerf_kernel(const float* __restrict__ rays_o, const float* __restrict__ rays_d,
                 const float* __restrict__ W1, const float* __restrict__ b1,
                 const unsigned int* __restrict__ wq, const float* __restrict__ b2,
                 const float* __restrict__ Wsig, const float* __restrict__ Wrgb,
                 const float* __restrict__ brgb,
                 float* __restrict__ out_depth, float* __restrict__ out_img,
                 int nRays)
{
    __shared__ __align__(16) float4 sW1t[64];
    __shared__ __align__(16) float4 sHD[64];
    __shared__ float sB2[64];
    __shared__ RayLds rl[4];

    const int tid  = threadIdx.x;
    const int lane = tid & 63;
    const int wv   = tid >> 6;

    // --- stage small weight tables (whole block) ---
    if (tid < 64) {
        sW1t[tid] = make_float4(W1[tid], W1[64 + tid], W1[128 + tid], b1[tid]);
        sHD[tid]  = make_float4(Wsig[tid], Wrgb[tid * 3 + 0], Wrgb[tid * 3 + 1], Wrgb[tid * 3 + 2]);
        sB2[tid]  = b2[tid];
    }
    __syncthreads();

    int ray = blockIdx.x * 4 + wv;
    bool valid = ray < nRays;
    int rayc = valid ? ray : (nRays - 1);
    RayLds& R = rl[wv];

    const float ox = rays_o[rayc * 3 + 0], oy = rays_o[rayc * 3 + 1], oz = rays_o[rayc * 3 + 2];
    const float dx = rays_d[rayc * 3 + 0], dy = rays_d[rayc * 3 + 1], dzv = rays_d[rayc * 3 + 2];

    // --- near/far vs cube [-2,2]^3 ---
    float t0x = (-BOUNDF - ox) / (dx + 1e-15f), t1x = (BOUNDF - ox) / (dx + 1e-15f);
    float t0y = (-BOUNDF - oy) / (dy + 1e-15f), t1y = (BOUNDF - oy) / (dy + 1e-15f);
    float t0z = (-BOUNDF - oz) / (dzv + 1e-15f), t1z = (BOUNDF - oz) / (dzv + 1e-15f);
    float nearv = fmaxf(fminf(t0x, t1x), fmaxf(fminf(t0y, t1y), fminf(t0z, t1z)));
    float farv  = fminf(fmaxf(t0x, t1x), fminf(fmaxf(t0y, t1y), fmaxf(t0z, t1z)));
    if (farv < nearv) { nearv = 1e9f; farv = 1e9f; }
    nearv = fmaxf(nearv, 0.05f);
    const float span = farv - nearv;
    const float dzc = span * (1.0f / 127.0f);
    const float sample_dist = span * (1.0f / 128.0f);

    // per-ray rgb bias: brgb + dirs @ Wrgb[64:67]
    const float base_r = brgb[0] + dx * Wrgb[64 * 3 + 0] + dy * Wrgb[65 * 3 + 0] + dzv * Wrgb[66 * 3 + 0];
    const float base_g = brgb[1] + dx * Wrgb[64 * 3 + 1] + dy * Wrgb[65 * 3 + 1] + dzv * Wrgb[66 * 3 + 1];
    const float base_b = brgb[2] + dx * Wrgb[64 * 3 + 2] + dy * Wrgb[65 * 3 + 2] + dzv * Wrgb[66 * 3 + 2];

    const int s0 = lane, s1 = lane + 64;

    // --- coarse eval: samples s0 (A) and s1 (B) per lane ---
    {
        float zA = fmaf(span, (float)s0 * (1.0f / 127.0f), nearv);
        float zB = fmaf(span, (float)s1 * (1.0f / 127.0f), nearv);
        R.zc[s0] = zA; R.zc[s1] = zB;
        float pxA = fminf(fmaxf(fmaf(dx, zA, ox), -BOUNDF), BOUNDF);
        float pyA = fminf(fmaxf(fmaf(dy, zA, oy), -BOUNDF), BOUNDF);
        float pzA = fminf(fmaxf(fmaf(dzv, zA, oz), -BOUNDF), BOUNDF);
        float pxB = fminf(fmaxf(fmaf(dx, zB, ox), -BOUNDF), BOUNDF);
        float pyB = fminf(fmaxf(fmaf(dy, zB, oy), -BOUNDF), BOUNDF);
        float pzB = fminf(fmaxf(fmaf(dzv, zB, oz), -BOUNDF), BOUNDF);
        float sgA, rA, gA, bA, sgB, rB, gB, bB;
        eval_field2(pxA, pyA, pzA, pxB, pyB, pzB, sW1t, wq, sHD, sB2,
                    base_r, base_g, base_b, sgA, rA, gA, bA, sgB, rB, gB, bB);
        R.sgc[s0] = sgA; R.rgbc[s0][0] = rA; R.rgbc[s0][1] = gA; R.rgbc[s0][2] = bA;
        R.sgc[s1] = sgB; R.rgbc[s1][0] = rB; R.rgbc[s1][1] = gB; R.rgbc[s1][2] = bB;

        // coarse alphas (deltas from actual z, matching reference)
        float znA = R.zc[s0 + 1];
        int   snB = (s1 < 127) ? s1 + 1 : 127;
        float znB = R.zc[snB];
        float dA = znA - zA;
        float dB = (s1 < 127) ? (znB - zB) : sample_dist;
        R.scr[s0] = 1.0f - __expf(-dA * sgA);
        R.scr[s1] = 1.0f - __expf(-dB * sgB);
    }

    // --- wave-parallel cumprod: weights for elements 2l, 2l+1 ---
    {
        float aa = R.scr[2 * lane], ab = R.scr[2 * lane + 1];
        float ma = 1.0f - aa + 1e-15f, mb = 1.0f - ab + 1e-15f;
        float p = scan_incl_mul(ma * mb, lane);
        float T0 = __shfl_up(p, 1, 64);
        if (lane == 0) T0 = 1.0f;
        R.scr[2 * lane]     = aa * T0;
        R.scr[2 * lane + 1] = ab * (T0 * ma);
    }

    // --- wave-parallel CDF over pdf[m]=w[1+m]+1e-5, m=0..125 ---
    {
        float pA = 0.f, pB = 0.f;
        if (lane < 63) {
            pA = R.scr[2 * lane + 1] + 1e-5f;
            pB = R.scr[2 * lane + 2] + 1e-5f;
        }
        float S = scan_incl_add(pA + pB, lane);
        float total = __shfl(S, 63, 64);
        float sexcl = __shfl_up(S, 1, 64);
        if (lane == 0) sexcl = 0.f;
        float inv = 1.0f / total;
        if (lane == 63) {
            R.cdf[0] = 0.0f;
        } else {
            R.cdf[1 + 2 * lane] = (sexcl + pA) * inv;
            R.cdf[2 + 2 * lane] = (sexcl + pA + pB) * inv;
        }
    }

    // --- inverse-CDF sampling: i0=lane, i1=lane+64 ---
#pragma unroll
    for (int bt = 0; bt < 2; ++bt) {
        int i = bt * 64 + lane;
        float u = (float)(2 * i + 1) * (1.0f / 256.0f);
        int lo = 0, hi = 127;   // searchsorted right over cdf[0..126]
        while (lo < hi) { int mid = (lo + hi) >> 1; if (R.cdf[mid] <= u) lo = mid + 1; else hi = mid; }
        int below = max(lo - 1, 0), above = min(lo, 126);
        float cb = R.cdf[below], ca = R.cdf[above];
        float binb = fmaf(dzc, (float)below + 0.5f, nearv);
        float bina = fmaf(dzc, (float)above + 0.5f, nearv);
        float denom = ca - cb;
        if (denom < 1e-5f) denom = 1.0f;
        float t = (u - cb) / denom;
        R.zf[i] = fmaf(t, bina - binb, binb);
    }

    // --- fine eval: samples s0 (A) and s1 (B) per lane ---
    {
        float zA = R.zf[s0], zB = R.zf[s1];
        float pxA = fminf(fmaxf(fmaf(dx, zA, ox), -BOUNDF), BOUNDF);
        float pyA = fminf(fmaxf(fmaf(dy, zA, oy), -BOUNDF), BOUNDF);
        float pzA = fminf(fmaxf(fmaf(dzv, zA, oz), -BOUNDF), BOUNDF);
        float pxB = fminf(fmaxf(fmaf(dx, zB, ox), -BOUNDF), BOUNDF);
        float pyB = fminf(fmaxf(fmaf(dy, zB, oy), -BOUNDF), BOUNDF);
        float pzB = fminf(fmaxf(fmaf(dzv, zB, oz), -BOUNDF), BOUNDF);
        float sgA, rA, gA, bA, sgB, rB, gB, bB;
        eval_field2(pxA, pyA, pzA, pxB, pyB, pzB, sW1t, wq, sHD, sB2,
                    base_r, base_g, base_b, sgA, rA, gA, bA, sgB, rB, gB, bB);
        R.sgf[s0] = sgA; R.rgbf[s0][0] = rA; R.rgbf[s0][1] = gA; R.rgbf[s0][2] = bA;
        R.sgf[s1] = sgB; R.rgbf[s1][0] = rB; R.rgbf[s1][1] = gB; R.rgbf[s1][2] = bB;
    }

    // --- stable merge of two sorted length-128 lists (merge-path ranks) ---
#pragma unroll
    for (int bt = 0; bt < 2; ++bt) {
        int k = bt * 64 + lane;
        float v = R.zc[k];
        int lo = 0, hi = 128;
        while (lo < hi) { int mid = (lo + hi) >> 1; if (R.zf[mid] < v) lo = mid + 1; else hi = mid; }
        R.perm[k + lo] = (unsigned short)k;
        float vf = R.zf[k];
        lo = 0; hi = 128;
        while (lo < hi) { int mid = (lo + hi) >> 1; if (R.zc[mid] <= vf) lo = mid + 1; else hi = mid; }
        R.perm[k + lo] = (unsigned short)(128 + k);
    }

    // --- merged composite: 4 samples per lane, scan + accumulate in regs ---
    {
        int sb = 4 * lane;
        int idxk[4]; float zk[4], sgk[4];
#pragma unroll
        for (int k = 0; k < 4; ++k) {
            int idx = R.perm[sb + k];
            idxk[k] = idx;
            zk[k]  = (idx < 128) ? R.zc[idx]  : R.zf[idx - 128];
            sgk[k] = (idx < 128) ? R.sgc[idx] : R.sgf[idx - 128];
        }
        float znext = __shfl_down(zk[0], 1, 64);   // z of sample 4l+4
        float d0 = zk[1] - zk[0];
        float d1 = zk[2] - zk[1];
        float d2 = zk[3] - zk[2];
        float d3 = (lane < 63) ? (znext - zk[3]) : sample_dist;
        float a0 = 1.0f - __expf(-d0 * sgk[0]);
        float a1 = 1.0f - __expf(-d1 * sgk[1]);
        float a2 = 1.0f - __expf(-d2 * sgk[2]);
        float a3 = 1.0f - __expf(-d3 * sgk[3]);
        float m0 = 1.0f - a0 + 1e-15f, m1 = 1.0f - a1 + 1e-15f;
        float m2 = 1.0f - a2 + 1e-15f, m3 = 1.0f - a3 + 1e-15f;
        float p = scan_incl_mul((m0 * m1) * (m2 * m3), lane);
        float T = __shfl_up(p, 1, 64);
        if (lane == 0) T = 1.0f;

        const float invspan = 1.0f / span;  // span==0 -> inf; 0*inf = NaN (matches jnp)
        float dacc = 0.f, racc = 0.f, gacc = 0.f, bacc = 0.f, wacc = 0.f;
        float aarr[4] = {a0, a1, a2, a3};
        float marr[4] = {m0, m1, m2, m3};
#pragma unroll
        for (int k = 0; k < 4; ++k) {
            float w = aarr[k] * T;
            float ozv = (zk[k] - nearv) * invspan;
            ozv = (ozv < 0.0f) ? 0.0f : ((ozv > 1.0f) ? 1.0f : ozv);  // NaN propagates
            dacc = fmaf(w, ozv, dacc);
            const float* rgb = (idxk[k] < 128) ? R.rgbc[idxk[k]] : R.rgbf[idxk[k] - 128];
            racc = fmaf(w, rgb[0], racc);
            gacc = fmaf(w, rgb[1], gacc);
            bacc = fmaf(w, rgb[2], bacc);
            wacc += w;
            T *= marr[k];
        }
#pragma unroll
        for (int off = 32; off; off >>= 1) {
            dacc += __shfl_xor(dacc, off);
            racc += __shfl_xor(racc, off);
            gacc += __shfl_xor(gacc, off);
            bacc += __shfl_xor(bacc, off);
            wacc += __shfl_xor(wacc, off);
        }
        if (lane == 0 && valid) {
            out_depth[ray] = dacc;
            float bg = 1.0f - wacc;
            out_img[ray * 3 + 0] = racc + bg;
            out_img[ray * 3 + 1] = gacc + bg;
            out_img[ray * 3 + 2] = bacc + bg;
        }
    }
}

extern "C" void kernel_launch(void* const* d_in, const int* in_sizes, int n_in,
                              void* d_out, int out_size, void* d_ws, size_t ws_size,
                              hipStream_t stream) {
    const float* rays_o = (const float*)d_in[0];
    const float* rays_d = (const float*)d_in[1];
    const float* W1   = (const float*)d_in[2];
    const float* b1   = (const float*)d_in[3];
    const float* W2   = (const float*)d_in[4];
    const float* b2   = (const float*)d_in[5];
    const float* Wsig = (const float*)d_in[6];
    const float* Wrgb = (const float*)d_in[7];
    const float* brgb = (const float*)d_in[8];

    int N = in_sizes[0] / 3;          // 4096 rays
    float* out = (float*)d_out;
    float* out_depth = out;           // [N]
    float* out_img   = out + N;       // [N,3]

    unsigned int* wq = (unsigned int*)d_ws;   // 2048 dwords = 8 KB packed fp16 W2

    prep_w2<<<dim3(8), dim3(256), 0, stream>>>(W2, wq);

    int blocks = (N + 3) / 4;
    nerf_kernel<<<dim3(blocks), dim3(256), 0, stream>>>(
        rays_o, rays_d, W1, b1, wq, b2, Wsig, Wrgb, brgb,
        out_depth, out_img, N);
}

// Round 10
// 195.645 us; speedup vs baseline: 1.7051x; 1.3101x over previous
//
#include <hip/hip_runtime.h>
#include <math.h>

// NeRF renderer: 4096 rays, 128+128 samples, tiny MLP field.
// One wave per ray. Layer 2 (h1[128x64] @ W2[64x64]) runs on the MATRIX pipe:
// mfma_f32_16x16x32_f16, with ALL of W2 held in 32 VGPRs as 8 B-fragments
// loaded once per wave (kills the per-row weight-load latency chain that
// bounded R7/R9 at ~195 us). h1 round-trips through wave-private LDS to reach
// A-fragment layout (A[m=lane&15][k=quad*8+j], verified mapping).
// D layout: col=lane&15 (=output unit n within tile), row=quad*4+reg (=sample).
//
// Spill discipline (R2..R8): no __launch_bounds__ min-waves arg (unreliable:
// caps too low -> 275-624 MB spill, or allocates 84 VGPR). No dynamic indexing
// of private arrays (R6: 5.9 GB scratch traffic). hbm_bytes <2 MB == clean.

#define BOUNDF 2.0f

typedef _Float16 f16;
typedef f16 f16x8 __attribute__((ext_vector_type(8)));
typedef float f32x4 __attribute__((ext_vector_type(4)));

struct RayLds {
    float zc[128];
    float zf[128];
    float sgc[128];
    float sgf[128];
    float rgbc[128][3];
    float rgbf[128][3];
    float cdf[128];
    float scr[128];
    unsigned short perm[256];
};

__device__ __forceinline__ float sigmoidf(float x) { return 1.0f / (1.0f + __expf(-x)); }

__device__ __forceinline__ f32x4 mfma16(f16x8 a, f16x8 b, f32x4 c) {
    return __builtin_amdgcn_mfma_f32_16x16x32_f16(a, b, c, 0, 0, 0);
}

__device__ __forceinline__ float scan_incl_mul(float p, int lane) {
#pragma unroll
    for (int off = 1; off < 64; off <<= 1) {
        float t = __shfl_up(p, off, 64);
        if (lane >= off) p *= t;
    }
    return p;
}

__device__ __forceinline__ float scan_incl_add(float p, int lane) {
#pragma unroll
    for (int off = 1; off < 64; off <<= 1) {
        float t = __shfl_up(p, off, 64);
        if (lane >= off) p += t;
    }
    return p;
}

// One field pass (128 samples) for one ray/wave, via MFMA.
// COARSE: z from linspace; else z = R.zf[m].
template<bool COARSE>
__device__ __forceinline__ void field_pass(
    RayLds& R, const float4* __restrict__ sW1t, f16* __restrict__ hbuf,
    f16x8 b00, f16x8 b01, f16x8 b10, f16x8 b11,
    f16x8 b20, f16x8 b21, f16x8 b30, f16x8 b31,
    f32x4 hd0, f32x4 hd1, f32x4 hd2, f32x4 hd3, f32x4 b2v,
    float ox, float oy, float oz, float dx, float dy, float dzv,
    float nearv, float span, float base_r, float base_g, float base_b, int lane)
{
    const int ms = lane & 15;          // sample-within-tile (A row / layer-1 role)
    const int quad = lane >> 4;
#pragma unroll 1
    for (int Mt = 0; Mt < 8; ++Mt) {
        int m = Mt * 16 + ms;
        float z = COARSE ? fmaf(span, (float)m * (1.0f / 127.0f), nearv) : R.zf[m];
        float px = fminf(fmaxf(fmaf(dx, z, ox), -BOUNDF), BOUNDF);
        float py = fminf(fmaxf(fmaf(dy, z, oy), -BOUNDF), BOUNDF);
        float pz = fminf(fmaxf(fmaf(dzv, z, oz), -BOUNDF), BOUNDF);

        // layer 1: this lane computes units quad*16 .. quad*16+15 for sample ms
        f16 hv[16];   // constant-indexed only (R6 lesson)
#pragma unroll
        for (int i = 0; i < 16; ++i) {
            float4 w = sW1t[quad * 16 + i];
            hv[i] = (f16)fmaxf(fmaf(px, w.x, fmaf(py, w.y, fmaf(pz, w.z, w.w))), 0.0f);
        }
        f16x8 lo, hi;
#pragma unroll
        for (int i = 0; i < 8; ++i) { lo[i] = hv[i]; hi[i] = hv[8 + i]; }
        *(f16x8*)(hbuf + ms * 72 + quad * 16)     = lo;
        *(f16x8*)(hbuf + ms * 72 + quad * 16 + 8) = hi;

        // A fragments: row ms, k = ks*32 + quad*8 + j  (in-order DS, wave-private)
        f16x8 a0 = *(const f16x8*)(hbuf + ms * 72 + quad * 8);
        f16x8 a1 = *(const f16x8*)(hbuf + ms * 72 + 32 + quad * 8);

        f32x4 zero = {0.f, 0.f, 0.f, 0.f};
        f32x4 ac0 = mfma16(a1, b01, mfma16(a0, b00, zero));
        f32x4 ac1 = mfma16(a1, b11, mfma16(a0, b10, zero));
        f32x4 ac2 = mfma16(a1, b21, mfma16(a0, b20, zero));
        f32x4 ac3 = mfma16(a1, b31, mfma16(a0, b30, zero));

        // h2 = relu(D + b2), then 4-output dot + 16-lane butterfly reduce
        float h2a[4][4];
#pragma unroll
        for (int r = 0; r < 4; ++r) {
            h2a[0][r] = fmaxf(ac0[r] + b2v[0], 0.0f);
            h2a[1][r] = fmaxf(ac1[r] + b2v[1], 0.0f);
            h2a[2][r] = fmaxf(ac2[r] + b2v[2], 0.0f);
            h2a[3][r] = fmaxf(ac3[r] + b2v[3], 0.0f);
        }
#pragma unroll
        for (int r = 0; r < 4; ++r) {
            f32x4 t = h2a[0][r] * hd0;
            t += h2a[1][r] * hd1;
            t += h2a[2][r] * hd2;
            t += h2a[3][r] * hd3;
#pragma unroll
            for (int st = 1; st <= 8; st <<= 1) {
                t[0] += __shfl_xor(t[0], st, 64);
                t[1] += __shfl_xor(t[1], st, 64);
                t[2] += __shfl_xor(t[2], st, 64);
                t[3] += __shfl_xor(t[3], st, 64);
            }
            // t = (sigma_pre, c0, c1, c2) for sample Mt*16 + quad*4 + r
            float sg = fmaxf(t[0], 0.0f) + log1pf(__expf(-fabsf(t[0])));
            float rr = sigmoidf(t[1] + base_r);
            float gg = sigmoidf(t[2] + base_g);
            float bb = sigmoidf(t[3] + base_b);
            if (ms == 0) {
                int m2 = Mt * 16 + quad * 4 + r;
                if (COARSE) {
                    R.sgc[m2] = sg;
                    R.rgbc[m2][0] = rr; R.rgbc[m2][1] = gg; R.rgbc[m2][2] = bb;
                } else {
                    R.sgf[m2] = sg;
                    R.rgbf[m2][0] = rr; R.rgbf[m2][1] = gg; R.rgbf[m2][2] = bb;
                }
            }
        }
    }
}

__global__ __launch_bounds__(256)
void nerf_kernel(const float* __restrict__ rays_o, const float* __restrict__ rays_d,
                 const float* __restrict__ W1, const float* __restrict__ b1,
                 const float* __restrict__ W2, const float* __restrict__ b2,
                 const float* __restrict__ Wsig, const float* __restrict__ Wrgb,
                 const float* __restrict__ brgb,
                 float* __restrict__ out_depth, float* __restrict__ out_img,
                 int nRays)
{
    __shared__ __align__(16) float4 sW1t[64];
    __shared__ __align__(16) f16 hbuf[4][16 * 72];   // per-wave h1 staging (stride 72 f16)
    __shared__ RayLds rl[4];

    const int tid  = threadIdx.x;
    const int lane = tid & 63;
    const int wv   = tid >> 6;
    const int ms   = lane & 15;
    const int quad = lane >> 4;

    if (tid < 64) {
        sW1t[tid] = make_float4(W1[tid], W1[64 + tid], W1[128 + tid], b1[tid]);
    }
    __syncthreads();

    // --- W2 as 8 MFMA B-fragments, resident in VGPRs for the whole kernel ---
    // B[k][n]: lane holds n = nt*16 + ms, k = ks*32 + quad*8 + j
    f16x8 b00, b01, b10, b11, b20, b21, b30, b31;
#pragma unroll
    for (int j = 0; j < 8; ++j) {
        int krow = (quad * 8 + j) * 64;
        b00[j] = (f16)W2[krow + ms];
        b10[j] = (f16)W2[krow + 16 + ms];
        b20[j] = (f16)W2[krow + 32 + ms];
        b30[j] = (f16)W2[krow + 48 + ms];
        b01[j] = (f16)W2[krow + 32 * 64 + ms];
        b11[j] = (f16)W2[krow + 32 * 64 + 16 + ms];
        b21[j] = (f16)W2[krow + 32 * 64 + 32 + ms];
        b31[j] = (f16)W2[krow + 32 * 64 + 48 + ms];
    }
    // head weights + b2, per-lane (n = nt*16 + ms)
    f32x4 hd0, hd1, hd2, hd3, b2v;
    {
        int n0 = ms, n1 = 16 + ms, n2 = 32 + ms, n3 = 48 + ms;
        hd0 = f32x4{Wsig[n0], Wrgb[n0 * 3], Wrgb[n0 * 3 + 1], Wrgb[n0 * 3 + 2]};
        hd1 = f32x4{Wsig[n1], Wrgb[n1 * 3], Wrgb[n1 * 3 + 1], Wrgb[n1 * 3 + 2]};
        hd2 = f32x4{Wsig[n2], Wrgb[n2 * 3], Wrgb[n2 * 3 + 1], Wrgb[n2 * 3 + 2]};
        hd3 = f32x4{Wsig[n3], Wrgb[n3 * 3], Wrgb[n3 * 3 + 1], Wrgb[n3 * 3 + 2]};
        b2v = f32x4{b2[n0], b2[n1], b2[n2], b2[n3]};
    }

    int ray = blockIdx.x * 4 + wv;
    bool valid = ray < nRays;
    int rayc = valid ? ray : (nRays - 1);
    RayLds& R = rl[wv];
    f16* hb = hbuf[wv];

    const float ox = rays_o[rayc * 3 + 0], oy = rays_o[rayc * 3 + 1], oz = rays_o[rayc * 3 + 2];
    const float dx = rays_d[rayc * 3 + 0], dy = rays_d[rayc * 3 + 1], dzv = rays_d[rayc * 3 + 2];

    // --- near/far vs cube [-2,2]^3 ---
    float t0x = (-BOUNDF - ox) / (dx + 1e-15f), t1x = (BOUNDF - ox) / (dx + 1e-15f);
    float t0y = (-BOUNDF - oy) / (dy + 1e-15f), t1y = (BOUNDF - oy) / (dy + 1e-15f);
    float t0z = (-BOUNDF - oz) / (dzv + 1e-15f), t1z = (BOUNDF - oz) / (dzv + 1e-15f);
    float nearv = fmaxf(fminf(t0x, t1x), fmaxf(fminf(t0y, t1y), fminf(t0z, t1z)));
    float farv  = fminf(fmaxf(t0x, t1x), fminf(fmaxf(t0y, t1y), fmaxf(t0z, t1z)));
    if (farv < nearv) { nearv = 1e9f; farv = 1e9f; }
    nearv = fmaxf(nearv, 0.05f);
    const float span = farv - nearv;
    const float dzc = span * (1.0f / 127.0f);
    const float sample_dist = span * (1.0f / 128.0f);

    const float base_r = brgb[0] + dx * Wrgb[64 * 3 + 0] + dy * Wrgb[65 * 3 + 0] + dzv * Wrgb[66 * 3 + 0];
    const float base_g = brgb[1] + dx * Wrgb[64 * 3 + 1] + dy * Wrgb[65 * 3 + 1] + dzv * Wrgb[66 * 3 + 1];
    const float base_b = brgb[2] + dx * Wrgb[64 * 3 + 2] + dy * Wrgb[65 * 3 + 2] + dzv * Wrgb[66 * 3 + 2];

    const int s0 = lane, s1 = lane + 64;

    // z_vals
    R.zc[s0] = fmaf(span, (float)s0 * (1.0f / 127.0f), nearv);
    R.zc[s1] = fmaf(span, (float)s1 * (1.0f / 127.0f), nearv);

    // --- coarse field pass (MFMA) ---
    field_pass<true>(R, sW1t, hb, b00, b01, b10, b11, b20, b21, b30, b31,
                     hd0, hd1, hd2, hd3, b2v,
                     ox, oy, oz, dx, dy, dzv, nearv, span, base_r, base_g, base_b, lane);

    // --- coarse alphas ---
    {
        float zA = R.zc[s0], zB = R.zc[s1];
        float dA = R.zc[s0 + 1] - zA;
        float dB = (s1 < 127) ? (R.zc[s1 + 1] - zB) : sample_dist;
        R.scr[s0] = 1.0f - __expf(-dA * R.sgc[s0]);
        R.scr[s1] = 1.0f - __expf(-dB * R.sgf[0] * 0.0f - dB * R.sgc[s1]);  // = 1-exp(-dB*sgc[s1])
    }

    // --- wave-parallel cumprod: weights for elements 2l, 2l+1 ---
    {
        float aa = R.scr[2 * lane], ab = R.scr[2 * lane + 1];
        float ma = 1.0f - aa + 1e-15f, mb = 1.0f - ab + 1e-15f;
        float p = scan_incl_mul(ma * mb, lane);
        float T0 = __shfl_up(p, 1, 64);
        if (lane == 0) T0 = 1.0f;
        R.scr[2 * lane]     = aa * T0;
        R.scr[2 * lane + 1] = ab * (T0 * ma);
    }

    // --- wave-parallel CDF over pdf[m]=w[1+m]+1e-5, m=0..125 ---
    {
        float pA = 0.f, pB = 0.f;
        if (lane < 63) {
            pA = R.scr[2 * lane + 1] + 1e-5f;
            pB = R.scr[2 * lane + 2] + 1e-5f;
        }
        float S = scan_incl_add(pA + pB, lane);
        float total = __shfl(S, 63, 64);
        float sexcl = __shfl_up(S, 1, 64);
        if (lane == 0) sexcl = 0.f;
        float inv = 1.0f / total;
        if (lane == 63) {
            R.cdf[0] = 0.0f;
        } else {
            R.cdf[1 + 2 * lane] = (sexcl + pA) * inv;
            R.cdf[2 + 2 * lane] = (sexcl + pA + pB) * inv;
        }
    }

    // --- inverse-CDF sampling ---
#pragma unroll
    for (int bt = 0; bt < 2; ++bt) {
        int i = bt * 64 + lane;
        float u = (float)(2 * i + 1) * (1.0f / 256.0f);
        int lo = 0, hi = 127;
        while (lo < hi) { int mid = (lo + hi) >> 1; if (R.cdf[mid] <= u) lo = mid + 1; else hi = mid; }
        int below = max(lo - 1, 0), above = min(lo, 126);
        float cb = R.cdf[below], ca = R.cdf[above];
        float binb = fmaf(dzc, (float)below + 0.5f, nearv);
        float bina = fmaf(dzc, (float)above + 0.5f, nearv);
        float denom = ca - cb;
        if (denom < 1e-5f) denom = 1.0f;
        float t = (u - cb) / denom;
        R.zf[i] = fmaf(t, bina - binb, binb);
    }

    // --- fine field pass (MFMA) ---
    field_pass<false>(R, sW1t, hb, b00, b01, b10, b11, b20, b21, b30, b31,
                      hd0, hd1, hd2, hd3, b2v,
                      ox, oy, oz, dx, dy, dzv, nearv, span, base_r, base_g, base_b, lane);

    // --- stable merge of two sorted length-128 lists ---
#pragma unroll
    for (int bt = 0; bt < 2; ++bt) {
        int k = bt * 64 + lane;
        float v = R.zc[k];
        int lo = 0, hi = 128;
        while (lo < hi) { int mid = (lo + hi) >> 1; if (R.zf[mid] < v) lo = mid + 1; else hi = mid; }
        R.perm[k + lo] = (unsigned short)k;
        float vf = R.zf[k];
        lo = 0; hi = 128;
        while (lo < hi) { int mid = (lo + hi) >> 1; if (R.zc[mid] <= vf) lo = mid + 1; else hi = mid; }
        R.perm[k + lo] = (unsigned short)(128 + k);
    }

    // --- merged composite ---
    {
        int sb = 4 * lane;
        int idxk[4]; float zk[4], sgk[4];
#pragma unroll
        for (int k = 0; k < 4; ++k) {
            int idx = R.perm[sb + k];
            idxk[k] = idx;
            zk[k]  = (idx < 128) ? R.zc[idx]  : R.zf[idx - 128];
            sgk[k] = (idx < 128) ? R.sgc[idx] : R.sgf[idx - 128];
        }
        float znext = __shfl_down(zk[0], 1, 64);
        float d0 = zk[1] - zk[0];
        float d1 = zk[2] - zk[1];
        float d2 = zk[3] - zk[2];
        float d3 = (lane < 63) ? (znext - zk[3]) : sample_dist;
        float a0 = 1.0f - __expf(-d0 * sgk[0]);
        float a1 = 1.0f - __expf(-d1 * sgk[1]);
        float a2 = 1.0f - __expf(-d2 * sgk[2]);
        float a3 = 1.0f - __expf(-d3 * sgk[3]);
        float m0 = 1.0f - a0 + 1e-15f, m1 = 1.0f - a1 + 1e-15f;
        float m2 = 1.0f - a2 + 1e-15f, m3 = 1.0f - a3 + 1e-15f;
        float p = scan_incl_mul((m0 * m1) * (m2 * m3), lane);
        float T = __shfl_up(p, 1, 64);
        if (lane == 0) T = 1.0f;

        const float invspan = 1.0f / span;
        float dacc = 0.f, racc = 0.f, gacc = 0.f, bacc = 0.f, wacc = 0.f;
        float aarr[4] = {a0, a1, a2, a3};
        float marr[4] = {m0, m1, m2, m3};
#pragma unroll
        for (int k = 0; k < 4; ++k) {
            float w = aarr[k] * T;
            float ozv = (zk[k] - nearv) * invspan;
            ozv = (ozv < 0.0f) ? 0.0f : ((ozv > 1.0f) ? 1.0f : ozv);
            dacc = fmaf(w, ozv, dacc);
            const float* rgb = (idxk[k] < 128) ? R.rgbc[idxk[k]] : R.rgbf[idxk[k] - 128];
            racc = fmaf(w, rgb[0], racc);
            gacc = fmaf(w, rgb[1], gacc);
            bacc = fmaf(w, rgb[2], bacc);
            wacc += w;
            T *= marr[k];
        }
#pragma unroll
        for (int off = 32; off; off >>= 1) {
            dacc += __shfl_xor(dacc, off);
            racc += __shfl_xor(racc, off);
            gacc += __shfl_xor(gacc, off);
            bacc += __shfl_xor(bacc, off);
            wacc += __shfl_xor(wacc, off);
        }
        if (lane == 0 && valid) {
            out_depth[ray] = dacc;
            float bg = 1.0f - wacc;
            out_img[ray * 3 + 0] = racc + bg;
            out_img[ray * 3 + 1] = gacc + bg;
            out_img[ray * 3 + 2] = bacc + bg;
        }
    }
}

extern "C" void kernel_launch(void* const* d_in, const int* in_sizes, int n_in,
                              void* d_out, int out_size, void* d_ws, size_t ws_size,
                              hipStream_t stream) {
    const float* rays_o = (const float*)d_in[0];
    const float* rays_d = (const float*)d_in[1];
    const float* W1   = (const float*)d_in[2];
    const float* b1   = (const float*)d_in[3];
    const float* W2   = (const float*)d_in[4];
    const float* b2   = (const float*)d_in[5];
    const float* Wsig = (const float*)d_in[6];
    const float* Wrgb = (const float*)d_in[7];
    const float* brgb = (const float*)d_in[8];

    int N = in_sizes[0] / 3;          // 4096 rays
    float* out = (float*)d_out;
    float* out_depth = out;           // [N]
    float* out_img   = out + N;       // [N,3]

    int blocks = (N + 3) / 4;
    nerf_kernel<<<dim3(blocks), dim3(256), 0, stream>>>(
        rays_o, rays_d, W1, b1, W2, b2, Wsig, Wrgb, brgb,
        out_depth, out_img, N);
}

// Round 12
// 123.605 us; speedup vs baseline: 2.6988x; 1.5828x over previous
//
#include <hip/hip_runtime.h>
#include <math.h>

// NeRF renderer: 4096 rays, 128+128 samples, tiny MLP field.
// One wave per ray. Layer 2 on the MATRIX pipe with TRANSPOSED operands:
//   mfma(W2_frag, h1_frag) -> D = h2^T: col = lane&15 = SAMPLE,
//   row = n = nt*16 + quad*4 + reg.
// (A and B fragments of mfma_f32_16x16x32_f16 share the same lane mapping —
// lane&15 = row/col, k = quad*8+j — so the same W2 registers serve as the
// A-position operand. R10's passing bench verified both mappings.)
// Wins vs R10: lane-local head dot (no 16-lane butterfly), transcendentals
// once per tile (not 4x), layer-1 emits A-fragments directly (hbuf deleted).
//
// Spill discipline (R2..R8): no __launch_bounds__ min-waves arg (unreliable:
// caps too low -> 275-624 MB spill, or allocates 84 VGPR). No dynamic indexing
// of private arrays (R6: 5.9 GB scratch traffic). hbm_bytes <2 MB == clean.

#define BOUNDF 2.0f

typedef _Float16 f16;
typedef f16 f16x8 __attribute__((ext_vector_type(8)));
typedef float f32x4 __attribute__((ext_vector_type(4)));

struct RayLds {
    float zc[128];
    float zf[128];
    float sgc[128];
    float sgf[128];
    float rgbc[128][3];
    float rgbf[128][3];
    float cdf[128];
    float scr[128];
    unsigned short perm[256];
};

__device__ __forceinline__ float sigmoidf(float x) { return 1.0f / (1.0f + __expf(-x)); }

__device__ __forceinline__ f32x4 mfma16(f16x8 a, f16x8 b, f32x4 c) {
    return __builtin_amdgcn_mfma_f32_16x16x32_f16(a, b, c, 0, 0, 0);
}

__device__ __forceinline__ float scan_incl_mul(float p, int lane) {
#pragma unroll
    for (int off = 1; off < 64; off <<= 1) {
        float t = __shfl_up(p, off, 64);
        if (lane >= off) p *= t;
    }
    return p;
}

__device__ __forceinline__ float scan_incl_add(float p, int lane) {
#pragma unroll
    for (int off = 1; off < 64; off <<= 1) {
        float t = __shfl_up(p, off, 64);
        if (lane >= off) p += t;
    }
    return p;
}

// One field pass (128 samples) for one ray/wave, via transposed MFMA.
template<bool COARSE>
__device__ __forceinline__ void field_pass(
    RayLds& R, const float4* __restrict__ sW1t, const float4* __restrict__ sHD,
    f16x8 b00, f16x8 b01, f16x8 b10, f16x8 b11,
    f16x8 b20, f16x8 b21, f16x8 b30, f16x8 b31,
    f32x4 b2q0, f32x4 b2q1, f32x4 b2q2, f32x4 b2q3,
    float ox, float oy, float oz, float dx, float dy, float dzv,
    float nearv, float span, float base_r, float base_g, float base_b, int lane)
{
    const int ms = lane & 15;          // sample-within-tile
    const int quad = lane >> 4;
#pragma unroll 1
    for (int Mt = 0; Mt < 8; ++Mt) {
        int m = Mt * 16 + ms;
        float z = COARSE ? fmaf(span, (float)m * (1.0f / 127.0f), nearv) : R.zf[m];
        float px = fminf(fmaxf(fmaf(dx, z, ox), -BOUNDF), BOUNDF);
        float py = fminf(fmaxf(fmaf(dy, z, oy), -BOUNDF), BOUNDF);
        float pz = fminf(fmaxf(fmaf(dzv, z, oz), -BOUNDF), BOUNDF);

        // layer 1 directly into A-fragment slots: lane ms needs h1[sample ms]
        // at k = quad*8+j (a0) and 32+quad*8+j (a1)
        f16x8 a0, a1;
#pragma unroll
        for (int j = 0; j < 8; ++j) {
            float4 w = sW1t[quad * 8 + j];
            a0[j] = (f16)fmaxf(fmaf(px, w.x, fmaf(py, w.y, fmaf(pz, w.z, w.w))), 0.0f);
            float4 w2 = sW1t[32 + quad * 8 + j];
            a1[j] = (f16)fmaxf(fmaf(px, w2.x, fmaf(py, w2.y, fmaf(pz, w2.z, w2.w))), 0.0f);
        }

        // transposed MFMA: D[n][sample], n = nt*16 + quad*4 + reg
        f32x4 zero = {0.f, 0.f, 0.f, 0.f};
        f32x4 acc[4];
        acc[0] = mfma16(b01, a1, mfma16(b00, a0, zero));
        acc[1] = mfma16(b11, a1, mfma16(b10, a0, zero));
        acc[2] = mfma16(b21, a1, mfma16(b20, a0, zero));
        acc[3] = mfma16(b31, a1, mfma16(b30, a0, zero));
        f32x4 b2a[4] = {b2q0, b2q1, b2q2, b2q3};

        // lane-local head dot over its 16 h2 units
        float t0 = 0.f, t1 = 0.f, t2 = 0.f, t3 = 0.f;
#pragma unroll
        for (int nt = 0; nt < 4; ++nt) {
#pragma unroll
            for (int r = 0; r < 4; ++r) {
                float h2 = fmaxf(acc[nt][r] + b2a[nt][r], 0.0f);
                float4 hd = sHD[nt * 16 + quad * 4 + r];   // {Wsig, Wrgb0..2}
                t0 = fmaf(h2, hd.x, t0);
                t1 = fmaf(h2, hd.y, t1);
                t2 = fmaf(h2, hd.z, t2);
                t3 = fmaf(h2, hd.w, t3);
            }
        }
        // reduce across the 4 quads (same sample ms)
        t0 += __shfl_xor(t0, 16, 64); t0 += __shfl_xor(t0, 32, 64);
        t1 += __shfl_xor(t1, 16, 64); t1 += __shfl_xor(t1, 32, 64);
        t2 += __shfl_xor(t2, 16, 64); t2 += __shfl_xor(t2, 32, 64);
        t3 += __shfl_xor(t3, 16, 64); t3 += __shfl_xor(t3, 32, 64);

        float sg = fmaxf(t0, 0.0f) + log1pf(__expf(-fabsf(t0)));
        float rr = sigmoidf(t1 + base_r);
        float gg = sigmoidf(t2 + base_g);
        float bb = sigmoidf(t3 + base_b);
        if (lane < 16) {
            if (COARSE) {
                R.sgc[m] = sg;
                R.rgbc[m][0] = rr; R.rgbc[m][1] = gg; R.rgbc[m][2] = bb;
            } else {
                R.sgf[m] = sg;
                R.rgbf[m][0] = rr; R.rgbf[m][1] = gg; R.rgbf[m][2] = bb;
            }
        }
    }
}

__global__ __launch_bounds__(256)
void nerf_kernel(const float* __restrict__ rays_o, const float* __restrict__ rays_d,
                 const float* __restrict__ W1, const float* __restrict__ b1,
                 const float* __restrict__ W2, const float* __restrict__ b2,
                 const float* __restrict__ Wsig, const float* __restrict__ Wrgb,
                 const float* __restrict__ brgb,
                 float* __restrict__ out_depth, float* __restrict__ out_img,
                 int nRays)
{
    __shared__ __align__(16) float4 sW1t[64];
    __shared__ __align__(16) float4 sHD[64];
    __shared__ RayLds rl[4];

    const int tid  = threadIdx.x;
    const int lane = tid & 63;
    const int wv   = tid >> 6;
    const int ms   = lane & 15;
    const int quad = lane >> 4;

    if (tid < 64) {
        sW1t[tid] = make_float4(W1[tid], W1[64 + tid], W1[128 + tid], b1[tid]);
        sHD[tid]  = make_float4(Wsig[tid], Wrgb[tid * 3 + 0], Wrgb[tid * 3 + 1], Wrgb[tid * 3 + 2]);
    }
    __syncthreads();

    // --- W2 as 8 MFMA fragments, resident in VGPRs (lane ms holds W2[k][nt*16+ms],
    //     k = quad*8+j (+32 for the *1 fragments)) ---
    f16x8 b00, b01, b10, b11, b20, b21, b30, b31;
#pragma unroll
    for (int j = 0; j < 8; ++j) {
        int krow = (quad * 8 + j) * 64;
        b00[j] = (f16)W2[krow + ms];
        b10[j] = (f16)W2[krow + 16 + ms];
        b20[j] = (f16)W2[krow + 32 + ms];
        b30[j] = (f16)W2[krow + 48 + ms];
        b01[j] = (f16)W2[krow + 32 * 64 + ms];
        b11[j] = (f16)W2[krow + 32 * 64 + 16 + ms];
        b21[j] = (f16)W2[krow + 32 * 64 + 32 + ms];
        b31[j] = (f16)W2[krow + 32 * 64 + 48 + ms];
    }
    // b2 per-lane: n = nt*16 + quad*4 + r
    f32x4 b2q0, b2q1, b2q2, b2q3;
#pragma unroll
    for (int r = 0; r < 4; ++r) {
        b2q0[r] = b2[quad * 4 + r];
        b2q1[r] = b2[16 + quad * 4 + r];
        b2q2[r] = b2[32 + quad * 4 + r];
        b2q3[r] = b2[48 + quad * 4 + r];
    }

    int ray = blockIdx.x * 4 + wv;
    bool valid = ray < nRays;
    int rayc = valid ? ray : (nRays - 1);
    RayLds& R = rl[wv];

    const float ox = rays_o[rayc * 3 + 0], oy = rays_o[rayc * 3 + 1], oz = rays_o[rayc * 3 + 2];
    const float dx = rays_d[rayc * 3 + 0], dy = rays_d[rayc * 3 + 1], dzv = rays_d[rayc * 3 + 2];

    // --- near/far vs cube [-2,2]^3 ---
    float t0x = (-BOUNDF - ox) / (dx + 1e-15f), t1x = (BOUNDF - ox) / (dx + 1e-15f);
    float t0y = (-BOUNDF - oy) / (dy + 1e-15f), t1y = (BOUNDF - oy) / (dy + 1e-15f);
    float t0z = (-BOUNDF - oz) / (dzv + 1e-15f), t1z = (BOUNDF - oz) / (dzv + 1e-15f);
    float nearv = fmaxf(fminf(t0x, t1x), fmaxf(fminf(t0y, t1y), fminf(t0z, t1z)));
    float farv  = fminf(fmaxf(t0x, t1x), fminf(fmaxf(t0y, t1y), fmaxf(t0z, t1z)));
    if (farv < nearv) { nearv = 1e9f; farv = 1e9f; }
    nearv = fmaxf(nearv, 0.05f);
    const float span = farv - nearv;
    const float dzc = span * (1.0f / 127.0f);
    const float sample_dist = span * (1.0f / 128.0f);

    const float base_r = brgb[0] + dx * Wrgb[64 * 3 + 0] + dy * Wrgb[65 * 3 + 0] + dzv * Wrgb[66 * 3 + 0];
    const float base_g = brgb[1] + dx * Wrgb[64 * 3 + 1] + dy * Wrgb[65 * 3 + 1] + dzv * Wrgb[66 * 3 + 1];
    const float base_b = brgb[2] + dx * Wrgb[64 * 3 + 2] + dy * Wrgb[65 * 3 + 2] + dzv * Wrgb[66 * 3 + 2];

    const int s0 = lane, s1 = lane + 64;

    // z_vals
    R.zc[s0] = fmaf(span, (float)s0 * (1.0f / 127.0f), nearv);
    R.zc[s1] = fmaf(span, (float)s1 * (1.0f / 127.0f), nearv);

    // --- coarse field pass (MFMA) ---
    field_pass<true>(R, sW1t, sHD, b00, b01, b10, b11, b20, b21, b30, b31,
                     b2q0, b2q1, b2q2, b2q3,
                     ox, oy, oz, dx, dy, dzv, nearv, span, base_r, base_g, base_b, lane);

    // --- coarse alphas ---
    {
        float zA = R.zc[s0], zB = R.zc[s1];
        float dA = R.zc[s0 + 1] - zA;
        float dB = (s1 < 127) ? (R.zc[s1 + 1] - zB) : sample_dist;
        R.scr[s0] = 1.0f - __expf(-dA * R.sgc[s0]);
        R.scr[s1] = 1.0f - __expf(-dB * R.sgc[s1]);
    }

    // --- wave-parallel cumprod: weights for elements 2l, 2l+1 ---
    {
        float aa = R.scr[2 * lane], ab = R.scr[2 * lane + 1];
        float ma = 1.0f - aa + 1e-15f, mb = 1.0f - ab + 1e-15f;
        float p = scan_incl_mul(ma * mb, lane);
        float T0 = __shfl_up(p, 1, 64);
        if (lane == 0) T0 = 1.0f;
        R.scr[2 * lane]     = aa * T0;
        R.scr[2 * lane + 1] = ab * (T0 * ma);
    }

    // --- wave-parallel CDF over pdf[m]=w[1+m]+1e-5, m=0..125 ---
    {
        float pA = 0.f, pB = 0.f;
        if (lane < 63) {
            pA = R.scr[2 * lane + 1] + 1e-5f;
            pB = R.scr[2 * lane + 2] + 1e-5f;
        }
        float S = scan_incl_add(pA + pB, lane);
        float total = __shfl(S, 63, 64);
        float sexcl = __shfl_up(S, 1, 64);
        if (lane == 0) sexcl = 0.f;
        float inv = 1.0f / total;
        if (lane == 63) {
            R.cdf[0] = 0.0f;
        } else {
            R.cdf[1 + 2 * lane] = (sexcl + pA) * inv;
            R.cdf[2 + 2 * lane] = (sexcl + pA + pB) * inv;
        }
    }

    // --- inverse-CDF sampling ---
#pragma unroll
    for (int bt = 0; bt < 2; ++bt) {
        int i = bt * 64 + lane;
        float u = (float)(2 * i + 1) * (1.0f / 256.0f);
        int lo = 0, hi = 127;
        while (lo < hi) { int mid = (lo + hi) >> 1; if (R.cdf[mid] <= u) lo = mid + 1; else hi = mid; }
        int below = max(lo - 1, 0), above = min(lo, 126);
        float cb = R.cdf[below], ca = R.cdf[above];
        float binb = fmaf(dzc, (float)below + 0.5f, nearv);
        float bina = fmaf(dzc, (float)above + 0.5f, nearv);
        float denom = ca - cb;
        if (denom < 1e-5f) denom = 1.0f;
        float t = (u - cb) / denom;
        R.zf[i] = fmaf(t, bina - binb, binb);
    }

    // --- fine field pass (MFMA) ---
    field_pass<false>(R, sW1t, sHD, b00, b01, b10, b11, b20, b21, b30, b31,
                      b2q0, b2q1, b2q2, b2q3,
                      ox, oy, oz, dx, dy, dzv, nearv, span, base_r, base_g, base_b, lane);

    // --- stable merge of two sorted length-128 lists ---
#pragma unroll
    for (int bt = 0; bt < 2; ++bt) {
        int k = bt * 64 + lane;
        float v = R.zc[k];
        int lo = 0, hi = 128;
        while (lo < hi) { int mid = (lo + hi) >> 1; if (R.zf[mid] < v) lo = mid + 1; else hi = mid; }
        R.perm[k + lo] = (unsigned short)k;
        float vf = R.zf[k];
        lo = 0; hi = 128;
        while (lo < hi) { int mid = (lo + hi) >> 1; if (R.zc[mid] <= vf) lo = mid + 1; else hi = mid; }
        R.perm[k + lo] = (unsigned short)(128 + k);
    }

    // --- merged composite ---
    {
        int sb = 4 * lane;
        int idxk[4]; float zk[4], sgk[4];
#pragma unroll
        for (int k = 0; k < 4; ++k) {
            int idx = R.perm[sb + k];
            idxk[k] = idx;
            zk[k]  = (idx < 128) ? R.zc[idx]  : R.zf[idx - 128];
            sgk[k] = (idx < 128) ? R.sgc[idx] : R.sgf[idx - 128];
        }
        float znext = __shfl_down(zk[0], 1, 64);
        float d0 = zk[1] - zk[0];
        float d1 = zk[2] - zk[1];
        float d2 = zk[3] - zk[2];
        float d3 = (lane < 63) ? (znext - zk[3]) : sample_dist;
        float a0 = 1.0f - __expf(-d0 * sgk[0]);
        float a1 = 1.0f - __expf(-d1 * sgk[1]);
        float a2 = 1.0f - __expf(-d2 * sgk[2]);
        float a3 = 1.0f - __expf(-d3 * sgk[3]);
        float m0 = 1.0f - a0 + 1e-15f, m1 = 1.0f - a1 + 1e-15f;
        float m2 = 1.0f - a2 + 1e-15f, m3 = 1.0f - a3 + 1e-15f;
        float p = scan_incl_mul((m0 * m1) * (m2 * m3), lane);
        float T = __shfl_up(p, 1, 64);
        if (lane == 0) T = 1.0f;

        const float invspan = 1.0f / span;
        float dacc = 0.f, racc = 0.f, gacc = 0.f, bacc = 0.f, wacc = 0.f;
        float aarr[4] = {a0, a1, a2, a3};
        float marr[4] = {m0, m1, m2, m3};
#pragma unroll
        for (int k = 0; k < 4; ++k) {
            float w = aarr[k] * T;
            float ozv = (zk[k] - nearv) * invspan;
            ozv = (ozv < 0.0f) ? 0.0f : ((ozv > 1.0f) ? 1.0f : ozv);
            dacc = fmaf(w, ozv, dacc);
            const float* rgb = (idxk[k] < 128) ? R.rgbc[idxk[k]] : R.rgbf[idxk[k] - 128];
            racc = fmaf(w, rgb[0], racc);
            gacc = fmaf(w, rgb[1], gacc);
            bacc = fmaf(w, rgb[2], bacc);
            wacc += w;
            T *= marr[k];
        }
#pragma unroll
        for (int off = 32; off; off >>= 1) {
            dacc += __shfl_xor(dacc, off);
            racc += __shfl_xor(racc, off);
            gacc += __shfl_xor(gacc, off);
            bacc += __shfl_xor(bacc, off);
            wacc += __shfl_xor(wacc, off);
        }
        if (lane == 0 && valid) {
            out_depth[ray] = dacc;
            float bg = 1.0f - wacc;
            out_img[ray * 3 + 0] = racc + bg;
            out_img[ray * 3 + 1] = gacc + bg;
            out_img[ray * 3 + 2] = bacc + bg;
        }
    }
}

extern "C" void kernel_launch(void* const* d_in, const int* in_sizes, int n_in,
                              void* d_out, int out_size, void* d_ws, size_t ws_size,
                              hipStream_t stream) {
    const float* rays_o = (const float*)d_in[0];
    const float* rays_d = (const float*)d_in[1];
    const float* W1   = (const float*)d_in[2];
    const float* b1   = (const float*)d_in[3];
    const float* W2   = (const float*)d_in[4];
    const float* b2   = (const float*)d_in[5];
    const float* Wsig = (const float*)d_in[6];
    const float* Wrgb = (const float*)d_in[7];
    const float* brgb = (const float*)d_in[8];

    int N = in_sizes[0] / 3;          // 4096 rays
    float* out = (float*)d_out;
    float* out_depth = out;           // [N]
    float* out_img   = out + N;       // [N,3]

    int blocks = (N + 3) / 4;
    nerf_kernel<<<dim3(blocks), dim3(256), 0, stream>>>(
        rays_o, rays_d, W1, b1, W2, b2, Wsig, Wrgb, brgb,
        out_depth, out_img, N);
}

// Round 13
// 121.792 us; speedup vs baseline: 2.7390x; 1.0149x over previous
//
#include <hip/hip_runtime.h>
#include <math.h>

// NeRF renderer: 4096 rays, 128+128 samples, tiny MLP field.
// One wave per ray. BOTH layer 2 AND the output head run on the matrix pipe.
//
// Layer 2 (transposed): mfma(W2_frag, h1_frag) -> D = h2^T with
//   col = lane&15 = SAMPLE, row = quad*4 + reg = physical unit slot.
// Unit-permutation trick: W2's output-unit order is arbitrary if HD/b2 use the
// same order. We load W2 columns permuted as u = 32*(nt>>1) + 8*quad +
// 4*(nt&1) + r so that the D' physical layout IS the B-fragment layout the
// head MFMA needs (k = quad*8 + j + 32*frag) — zero cross-lane rearrangement.
// Head: mfma(HD_frag, h2_frag) -> all 4 outputs for sample s land in lane
// (quad0, s) regs 0..3. No reduce shuffles; transcendentals on 16 lanes only.
// b2 is folded into the layer-2 MFMA C-operand (D = A@B + C).
//
// Spill discipline (R2..R8): no __launch_bounds__ min-waves arg (unreliable:
// caps too low -> 275-624 MB spill, or allocates 84 VGPR). No dynamic indexing
// of private arrays (R6: 5.9 GB scratch traffic). hbm_bytes <2 MB == clean.

#define BOUNDF 2.0f

typedef _Float16 f16;
typedef f16 f16x8 __attribute__((ext_vector_type(8)));
typedef float f32x4 __attribute__((ext_vector_type(4)));

struct RayLds {
    float zc[128];
    float zf[128];
    float sgc[128];
    float sgf[128];
    float rgbc[128][3];
    float rgbf[128][3];
    float cdf[128];
    float scr[128];
    unsigned short perm[256];
};

__device__ __forceinline__ float sigmoidf(float x) { return 1.0f / (1.0f + __expf(-x)); }

__device__ __forceinline__ f32x4 mfma16(f16x8 a, f16x8 b, f32x4 c) {
    return __builtin_amdgcn_mfma_f32_16x16x32_f16(a, b, c, 0, 0, 0);
}

__device__ __forceinline__ float scan_incl_mul(float p, int lane) {
#pragma unroll
    for (int off = 1; off < 64; off <<= 1) {
        float t = __shfl_up(p, off, 64);
        if (lane >= off) p *= t;
    }
    return p;
}

__device__ __forceinline__ float scan_incl_add(float p, int lane) {
#pragma unroll
    for (int off = 1; off < 64; off <<= 1) {
        float t = __shfl_up(p, off, 64);
        if (lane >= off) p += t;
    }
    return p;
}

// One field pass (128 samples) for one ray/wave, via double MFMA.
template<bool COARSE>
__device__ __forceinline__ void field_pass(
    RayLds& R, const float4* __restrict__ sW1t,
    f16x8 b00, f16x8 b01, f16x8 b10, f16x8 b11,
    f16x8 b20, f16x8 b21, f16x8 b30, f16x8 b31,
    f16x8 hda0, f16x8 hda1,
    f32x4 b2q0, f32x4 b2q1, f32x4 b2q2, f32x4 b2q3,
    float ox, float oy, float oz, float dx, float dy, float dzv,
    float nearv, float span, float base_r, float base_g, float base_b, int lane)
{
    const int ms = lane & 15;          // sample-within-tile
    const int quad = lane >> 4;
#pragma unroll 1
    for (int Mt = 0; Mt < 8; ++Mt) {
        int m = Mt * 16 + ms;
        float z = COARSE ? fmaf(span, (float)m * (1.0f / 127.0f), nearv) : R.zf[m];
        float px = fminf(fmaxf(fmaf(dx, z, ox), -BOUNDF), BOUNDF);
        float py = fminf(fmaxf(fmaf(dy, z, oy), -BOUNDF), BOUNDF);
        float pz = fminf(fmaxf(fmaf(dzv, z, oz), -BOUNDF), BOUNDF);

        // layer 1 directly into A-fragment slots: lane ms needs h1[sample ms]
        // at k = quad*8+j (a0) and 32+quad*8+j (a1)
        f16x8 a0, a1;
#pragma unroll
        for (int j = 0; j < 8; ++j) {
            float4 w = sW1t[quad * 8 + j];
            a0[j] = (f16)fmaxf(fmaf(px, w.x, fmaf(py, w.y, fmaf(pz, w.z, w.w))), 0.0f);
            float4 w2 = sW1t[32 + quad * 8 + j];
            a1[j] = (f16)fmaxf(fmaf(px, w2.x, fmaf(py, w2.y, fmaf(pz, w2.z, w2.w))), 0.0f);
        }

        // layer-2 MFMA (transposed, bias in C): acc_nt[r] = h2[phys (nt,quad,r)][ms]
        f32x4 acc0 = mfma16(b01, a1, mfma16(b00, a0, b2q0));
        f32x4 acc1 = mfma16(b11, a1, mfma16(b10, a0, b2q1));
        f32x4 acc2 = mfma16(b21, a1, mfma16(b20, a0, b2q2));
        f32x4 acc3 = mfma16(b31, a1, mfma16(b30, a0, b2q3));

        // relu + cvt: physical layout IS the head B-fragment layout (perm trick)
        f16x8 h0, h1f;
#pragma unroll
        for (int j = 0; j < 8; ++j) {
            float v0 = (j < 4) ? acc0[j & 3] : acc1[j & 3];
            float v1 = (j < 4) ? acc2[j & 3] : acc3[j & 3];
            h0[j]  = (f16)fmaxf(v0, 0.0f);
            h1f[j] = (f16)fmaxf(v1, 0.0f);
        }
        // head MFMA: D[o][s], o = quad*4+reg -> lane (quad0, s) regs 0..3
        f32x4 zero = {0.f, 0.f, 0.f, 0.f};
        f32x4 tv = mfma16(hda1, h1f, mfma16(hda0, h0, zero));

        if (lane < 16) {   // quad0: o = reg
            float sg = fmaxf(tv[0], 0.0f) + log1pf(__expf(-fabsf(tv[0])));
            float rr = sigmoidf(tv[1] + base_r);
            float gg = sigmoidf(tv[2] + base_g);
            float bb = sigmoidf(tv[3] + base_b);
            if (COARSE) {
                R.sgc[m] = sg;
                R.rgbc[m][0] = rr; R.rgbc[m][1] = gg; R.rgbc[m][2] = bb;
            } else {
                R.sgf[m] = sg;
                R.rgbf[m][0] = rr; R.rgbf[m][1] = gg; R.rgbf[m][2] = bb;
            }
        }
    }
}

__global__ __launch_bounds__(256)
void nerf_kernel(const float* __restrict__ rays_o, const float* __restrict__ rays_d,
                 const float* __restrict__ W1, const float* __restrict__ b1,
                 const float* __restrict__ W2, const float* __restrict__ b2,
                 const float* __restrict__ Wsig, const float* __restrict__ Wrgb,
                 const float* __restrict__ brgb,
                 float* __restrict__ out_depth, float* __restrict__ out_img,
                 int nRays)
{
    __shared__ __align__(16) float4 sW1t[64];
    __shared__ RayLds rl[4];

    const int tid  = threadIdx.x;
    const int lane = tid & 63;
    const int wv   = tid >> 6;
    const int ms   = lane & 15;
    const int quad = lane >> 4;

    if (tid < 64) {
        sW1t[tid] = make_float4(W1[tid], W1[64 + tid], W1[128 + tid], b1[tid]);
    }
    __syncthreads();

    // --- W2 as 8 MFMA fragments with PERMUTED unit columns:
    //     physical (nt, row m=ms) holds logical unit u = colbase + {0,4,32,36}[nt]
    //     where colbase = 8*(ms>>2) + (ms&3). ---
    const int colbase = 8 * (ms >> 2) + (ms & 3);
    f16x8 b00, b01, b10, b11, b20, b21, b30, b31;
#pragma unroll
    for (int j = 0; j < 8; ++j) {
        int k0 = (quad * 8 + j) * 64;
        int k1 = (32 + quad * 8 + j) * 64;
        b00[j] = (f16)W2[k0 + colbase];      b01[j] = (f16)W2[k1 + colbase];
        b10[j] = (f16)W2[k0 + colbase + 4];  b11[j] = (f16)W2[k1 + colbase + 4];
        b20[j] = (f16)W2[k0 + colbase + 32]; b21[j] = (f16)W2[k1 + colbase + 32];
        b30[j] = (f16)W2[k0 + colbase + 36]; b31[j] = (f16)W2[k1 + colbase + 36];
    }
    // b2 as C-operand vectors, same permutation: phys (nt,quad,r) = b2[u]
    f32x4 b2q0, b2q1, b2q2, b2q3;
#pragma unroll
    for (int r = 0; r < 4; ++r) {
        b2q0[r] = b2[8 * quad + r];
        b2q1[r] = b2[8 * quad + 4 + r];
        b2q2[r] = b2[32 + 8 * quad + r];
        b2q3[r] = b2[32 + 8 * quad + 4 + r];
    }
    // head weight A-fragments: A[o=ms][k=u]; only rows 0..3 meaningful
    // (rows 4..15 load garbage-but-valid values; their D rows are never read)
    f16x8 hda0, hda1;
    {
        int msel = ms & 3;
#pragma unroll
        for (int j = 0; j < 8; ++j) {
            int u0 = quad * 8 + j, u1 = 32 + quad * 8 + j;
            float w0 = (msel == 0) ? Wsig[u0] : Wrgb[u0 * 3 + msel - 1];
            float w1 = (msel == 0) ? Wsig[u1] : Wrgb[u1 * 3 + msel - 1];
            hda0[j] = (f16)w0;
            hda1[j] = (f16)w1;
        }
    }

    int ray = blockIdx.x * 4 + wv;
    bool valid = ray < nRays;
    int rayc = valid ? ray : (nRays - 1);
    RayLds& R = rl[wv];

    const float ox = rays_o[rayc * 3 + 0], oy = rays_o[rayc * 3 + 1], oz = rays_o[rayc * 3 + 2];
    const float dx = rays_d[rayc * 3 + 0], dy = rays_d[rayc * 3 + 1], dzv = rays_d[rayc * 3 + 2];

    // --- near/far vs cube [-2,2]^3 ---
    float t0x = (-BOUNDF - ox) / (dx + 1e-15f), t1x = (BOUNDF - ox) / (dx + 1e-15f);
    float t0y = (-BOUNDF - oy) / (dy + 1e-15f), t1y = (BOUNDF - oy) / (dy + 1e-15f);
    float t0z = (-BOUNDF - oz) / (dzv + 1e-15f), t1z = (BOUNDF - oz) / (dzv + 1e-15f);
    float nearv = fmaxf(fminf(t0x, t1x), fmaxf(fminf(t0y, t1y), fminf(t0z, t1z)));
    float farv  = fminf(fmaxf(t0x, t1x), fminf(fmaxf(t0y, t1y), fmaxf(t0z, t1z)));
    if (farv < nearv) { nearv = 1e9f; farv = 1e9f; }
    nearv = fmaxf(nearv, 0.05f);
    const float span = farv - nearv;
    const float dzc = span * (1.0f / 127.0f);
    const float sample_dist = span * (1.0f / 128.0f);

    const float base_r = brgb[0] + dx * Wrgb[64 * 3 + 0] + dy * Wrgb[65 * 3 + 0] + dzv * Wrgb[66 * 3 + 0];
    const float base_g = brgb[1] + dx * Wrgb[64 * 3 + 1] + dy * Wrgb[65 * 3 + 1] + dzv * Wrgb[66 * 3 + 1];
    const float base_b = brgb[2] + dx * Wrgb[64 * 3 + 2] + dy * Wrgb[65 * 3 + 2] + dzv * Wrgb[66 * 3 + 2];

    const int s0 = lane, s1 = lane + 64;

    // z_vals
    R.zc[s0] = fmaf(span, (float)s0 * (1.0f / 127.0f), nearv);
    R.zc[s1] = fmaf(span, (float)s1 * (1.0f / 127.0f), nearv);

    // --- coarse field pass (MFMA) ---
    field_pass<true>(R, sW1t, b00, b01, b10, b11, b20, b21, b30, b31,
                     hda0, hda1, b2q0, b2q1, b2q2, b2q3,
                     ox, oy, oz, dx, dy, dzv, nearv, span, base_r, base_g, base_b, lane);

    // --- coarse alphas ---
    {
        float zA = R.zc[s0], zB = R.zc[s1];
        float dA = R.zc[s0 + 1] - zA;
        float dB = (s1 < 127) ? (R.zc[s1 + 1] - zB) : sample_dist;
        R.scr[s0] = 1.0f - __expf(-dA * R.sgc[s0]);
        R.scr[s1] = 1.0f - __expf(-dB * R.sgc[s1]);
    }

    // --- wave-parallel cumprod: weights for elements 2l, 2l+1 ---
    {
        float aa = R.scr[2 * lane], ab = R.scr[2 * lane + 1];
        float ma = 1.0f - aa + 1e-15f, mb = 1.0f - ab + 1e-15f;
        float p = scan_incl_mul(ma * mb, lane);
        float T0 = __shfl_up(p, 1, 64);
        if (lane == 0) T0 = 1.0f;
        R.scr[2 * lane]     = aa * T0;
        R.scr[2 * lane + 1] = ab * (T0 * ma);
    }

    // --- wave-parallel CDF over pdf[m]=w[1+m]+1e-5, m=0..125 ---
    {
        float pA = 0.f, pB = 0.f;
        if (lane < 63) {
            pA = R.scr[2 * lane + 1] + 1e-5f;
            pB = R.scr[2 * lane + 2] + 1e-5f;
        }
        float S = scan_incl_add(pA + pB, lane);
        float total = __shfl(S, 63, 64);
        float sexcl = __shfl_up(S, 1, 64);
        if (lane == 0) sexcl = 0.f;
        float inv = 1.0f / total;
        if (lane == 63) {
            R.cdf[0] = 0.0f;
        } else {
            R.cdf[1 + 2 * lane] = (sexcl + pA) * inv;
            R.cdf[2 + 2 * lane] = (sexcl + pA + pB) * inv;
        }
    }

    // --- inverse-CDF sampling ---
#pragma unroll
    for (int bt = 0; bt < 2; ++bt) {
        int i = bt * 64 + lane;
        float u = (float)(2 * i + 1) * (1.0f / 256.0f);
        int lo = 0, hi = 127;
        while (lo < hi) { int mid = (lo + hi) >> 1; if (R.cdf[mid] <= u) lo = mid + 1; else hi = mid; }
        int below = max(lo - 1, 0), above = min(lo, 126);
        float cb = R.cdf[below], ca = R.cdf[above];
        float binb = fmaf(dzc, (float)below + 0.5f, nearv);
        float bina = fmaf(dzc, (float)above + 0.5f, nearv);
        float denom = ca - cb;
        if (denom < 1e-5f) denom = 1.0f;
        float t = (u - cb) / denom;
        R.zf[i] = fmaf(t, bina - binb, binb);
    }

    // --- fine field pass (MFMA) ---
    field_pass<false>(R, sW1t, b00, b01, b10, b11, b20, b21, b30, b31,
                      hda0, hda1, b2q0, b2q1, b2q2, b2q3,
                      ox, oy, oz, dx, dy, dzv, nearv, span, base_r, base_g, base_b, lane);

    // --- stable merge of two sorted length-128 lists ---
#pragma unroll
    for (int bt = 0; bt < 2; ++bt) {
        int k = bt * 64 + lane;
        float v = R.zc[k];
        int lo = 0, hi = 128;
        while (lo < hi) { int mid = (lo + hi) >> 1; if (R.zf[mid] < v) lo = mid + 1; else hi = mid; }
        R.perm[k + lo] = (unsigned short)k;
        float vf = R.zf[k];
        lo = 0; hi = 128;
        while (lo < hi) { int mid = (lo + hi) >> 1; if (R.zc[mid] <= vf) lo = mid + 1; else hi = mid; }
        R.perm[k + lo] = (unsigned short)(128 + k);
    }

    // --- merged composite ---
    {
        int sb = 4 * lane;
        int idxk[4]; float zk[4], sgk[4];
#pragma unroll
        for (int k = 0; k < 4; ++k) {
            int idx = R.perm[sb + k];
            idxk[k] = idx;
            zk[k]  = (idx < 128) ? R.zc[idx]  : R.zf[idx - 128];
            sgk[k] = (idx < 128) ? R.sgc[idx] : R.sgf[idx - 128];
        }
        float znext = __shfl_down(zk[0], 1, 64);
        float d0 = zk[1] - zk[0];
        float d1 = zk[2] - zk[1];
        float d2 = zk[3] - zk[2];
        float d3 = (lane < 63) ? (znext - zk[3]) : sample_dist;
        float a0 = 1.0f - __expf(-d0 * sgk[0]);
        float a1 = 1.0f - __expf(-d1 * sgk[1]);
        float a2 = 1.0f - __expf(-d2 * sgk[2]);
        float a3 = 1.0f - __expf(-d3 * sgk[3]);
        float m0 = 1.0f - a0 + 1e-15f, m1 = 1.0f - a1 + 1e-15f;
        float m2 = 1.0f - a2 + 1e-15f, m3 = 1.0f - a3 + 1e-15f;
        float p = scan_incl_mul((m0 * m1) * (m2 * m3), lane);
        float T = __shfl_up(p, 1, 64);
        if (lane == 0) T = 1.0f;

        const float invspan = 1.0f / span;
        float dacc = 0.f, racc = 0.f, gacc = 0.f, bacc = 0.f, wacc = 0.f;
        float aarr[4] = {a0, a1, a2, a3};
        float marr[4] = {m0, m1, m2, m3};
#pragma unroll
        for (int k = 0; k < 4; ++k) {
            float w = aarr[k] * T;
            float ozv = (zk[k] - nearv) * invspan;
            ozv = (ozv < 0.0f) ? 0.0f : ((ozv > 1.0f) ? 1.0f : ozv);
            dacc = fmaf(w, ozv, dacc);
            const float* rgb = (idxk[k] < 128) ? R.rgbc[idxk[k]] : R.rgbf[idxk[k] - 128];
            racc = fmaf(w, rgb[0], racc);
            gacc = fmaf(w, rgb[1], gacc);
            bacc = fmaf(w, rgb[2], bacc);
            wacc += w;
            T *= marr[k];
        }
#pragma unroll
        for (int off = 32; off; off >>= 1) {
            dacc += __shfl_xor(dacc, off);
            racc += __shfl_xor(racc, off);
            gacc += __shfl_xor(gacc, off);
            bacc += __shfl_xor(bacc, off);
            wacc += __shfl_xor(wacc, off);
        }
        if (lane == 0 && valid) {
            out_depth[ray] = dacc;
            float bg = 1.0f - wacc;
            out_img[ray * 3 + 0] = racc + bg;
            out_img[ray * 3 + 1] = gacc + bg;
            out_img[ray * 3 + 2] = bacc + bg;
        }
    }
}

extern "C" void kernel_launch(void* const* d_in, const int* in_sizes, int n_in,
                              void* d_out, int out_size, void* d_ws, size_t ws_size,
                              hipStream_t stream) {
    const float* rays_o = (const float*)d_in[0];
    const float* rays_d = (const float*)d_in[1];
    const float* W1   = (const float*)d_in[2];
    const float* b1   = (const float*)d_in[3];
    const float* W2   = (const float*)d_in[4];
    const float* b2   = (const float*)d_in[5];
    const float* Wsig = (const float*)d_in[6];
    const float* Wrgb = (const float*)d_in[7];
    const float* brgb = (const float*)d_in[8];

    int N = in_sizes[0] / 3;          // 4096 rays
    float* out = (float*)d_out;
    float* out_depth = out;           // [N]
    float* out_img   = out + N;       // [N,3]

    int blocks = (N + 3) / 4;
    nerf_kernel<<<dim3(blocks), dim3(256), 0, stream>>>(
        rays_o, rays_d, W1, b1, W2, b2, Wsig, Wrgb, brgb,
        out_depth, out_img, N);
}

// Round 14
// 106.547 us; speedup vs baseline: 3.1309x; 1.1431x over previous
//
#include <hip/hip_runtime.h>
#include <math.h>

// NeRF renderer: 4096 rays, 128+128 samples, tiny MLP field.
// One wave per ray. ALL THREE layers run on the matrix pipe:
//   L1: mfma(W1_frag, P_frag)  -> h1 (K=4 zero-padded to 32; b1 via P[3]=1)
//   L2: mfma(W2_frag, h1_frag) -> h2 (b2 in the C operand)
//   HD: mfma(HD_frag, h2_frag) -> {sigma_pre, c0, c1, c2} per sample
// Unit-permutation trick (verified R13): permute hidden-unit order so each
// MFMA's D-physical layout IS the next MFMA's B-fragment layout — zero
// cross-lane data movement. The index algebra collapses so W2/head/b2 loads
// are byte-identical to R13; only W1 is loaded with the permuted unit order
// u = 32*(nt>>1) + 8*(ms>>2) + 4*(nt&1) + (ms&3).
// Batched epilogue: tv staged to the (idle) cdf+scr LDS region, then every 4
// tiles all 64 lanes each finish one sample (4x fewer transcendental issues).
//
// Spill discipline (R2..R8): no __launch_bounds__ min-waves arg (unreliable:
// caps too low -> 275-624 MB spill, or allocates 84 VGPR). No dynamic indexing
// of private arrays (R6: 5.9 GB scratch traffic). hbm_bytes <2 MB == clean.

#define BOUNDF 2.0f

typedef _Float16 f16;
typedef f16 f16x8 __attribute__((ext_vector_type(8)));
typedef float f32x4 __attribute__((ext_vector_type(4)));

struct RayLds {
    float zc[128];
    float zf[128];
    float sgc[128];
    float sgf[128];
    float rgbc[128][3];
    float rgbf[128][3];
    float cdf[128];       // cdf+scr double as the 256-float epilogue stage
    float scr[128];       //   (must stay adjacent & 16B-aligned)
    unsigned short perm[256];
};

__device__ __forceinline__ float sigmoidf(float x) { return 1.0f / (1.0f + __expf(-x)); }

__device__ __forceinline__ f32x4 mfma16(f16x8 a, f16x8 b, f32x4 c) {
    return __builtin_amdgcn_mfma_f32_16x16x32_f16(a, b, c, 0, 0, 0);
}

__device__ __forceinline__ float scan_incl_mul(float p, int lane) {
#pragma unroll
    for (int off = 1; off < 64; off <<= 1) {
        float t = __shfl_up(p, off, 64);
        if (lane >= off) p *= t;
    }
    return p;
}

__device__ __forceinline__ float scan_incl_add(float p, int lane) {
#pragma unroll
    for (int off = 1; off < 64; off <<= 1) {
        float t = __shfl_up(p, off, 64);
        if (lane >= off) p += t;
    }
    return p;
}

// One field pass (128 samples) for one ray/wave, via triple MFMA.
template<bool COARSE>
__device__ __forceinline__ void field_pass(
    RayLds& R,
    f16x8 w1a0, f16x8 w1a1, f16x8 w1a2, f16x8 w1a3,
    f16x8 b00, f16x8 b01, f16x8 b10, f16x8 b11,
    f16x8 b20, f16x8 b21, f16x8 b30, f16x8 b31,
    f16x8 hda0, f16x8 hda1,
    f32x4 b2q0, f32x4 b2q1, f32x4 b2q2, f32x4 b2q3,
    float ox, float oy, float oz, float dx, float dy, float dzv,
    float nearv, float span, float base_r, float base_g, float base_b, int lane)
{
    const int ms = lane & 15;          // sample-within-tile
    f32x4* stage = (f32x4*)(&R.cdf[0]);   // 256 floats: cdf+scr (idle here)
    const f32x4 zero = {0.f, 0.f, 0.f, 0.f};
#pragma unroll 1
    for (int Mtb = 0; Mtb < 2; ++Mtb) {
#pragma unroll 1
        for (int Mti = 0; Mti < 4; ++Mti) {
            int m = Mtb * 64 + Mti * 16 + ms;
            float z = COARSE ? fmaf(span, (float)m * (1.0f / 127.0f), nearv) : R.zf[m];
            float px = fminf(fmaxf(fmaf(dx, z, ox), -BOUNDF), BOUNDF);
            float py = fminf(fmaxf(fmaf(dy, z, oy), -BOUNDF), BOUNDF);
            float pz = fminf(fmaxf(fmaf(dzv, z, oz), -BOUNDF), BOUNDF);

            // P B-fragment: only k=0..3 on quad0 matter (A is zero elsewhere)
            f16x8 pf;
            pf[0] = (f16)px; pf[1] = (f16)py; pf[2] = (f16)pz; pf[3] = (f16)1.0f;
            pf[4] = (f16)0.f; pf[5] = (f16)0.f; pf[6] = (f16)0.f; pf[7] = (f16)0.f;

            // layer-1 MFMA: hacc_nt[r] = h1pre[phys (nt,quad,r)][ms]
            f32x4 hacc0 = mfma16(w1a0, pf, zero);
            f32x4 hacc1 = mfma16(w1a1, pf, zero);
            f32x4 hacc2 = mfma16(w1a2, pf, zero);
            f32x4 hacc3 = mfma16(w1a3, pf, zero);

            // relu + cvt: physical layout IS the layer-2 B-fragment layout
            f16x8 hf0, hf1;
#pragma unroll
            for (int j = 0; j < 8; ++j) {
                float v0 = (j < 4) ? hacc0[j & 3] : hacc1[j & 3];
                float v1 = (j < 4) ? hacc2[j & 3] : hacc3[j & 3];
                hf0[j] = (f16)fmaxf(v0, 0.0f);
                hf1[j] = (f16)fmaxf(v1, 0.0f);
            }

            // layer-2 MFMA (bias in C): acc_nt[r] = h2[phys (nt,quad,r)][ms]
            f32x4 acc0 = mfma16(b01, hf1, mfma16(b00, hf0, b2q0));
            f32x4 acc1 = mfma16(b11, hf1, mfma16(b10, hf0, b2q1));
            f32x4 acc2 = mfma16(b21, hf1, mfma16(b20, hf0, b2q2));
            f32x4 acc3 = mfma16(b31, hf1, mfma16(b30, hf0, b2q3));

            // relu + cvt: physical layout IS the head B-fragment layout
            f16x8 h0, h1f;
#pragma unroll
            for (int j = 0; j < 8; ++j) {
                float v0 = (j < 4) ? acc0[j & 3] : acc1[j & 3];
                float v1 = (j < 4) ? acc2[j & 3] : acc3[j & 3];
                h0[j]  = (f16)fmaxf(v0, 0.0f);
                h1f[j] = (f16)fmaxf(v1, 0.0f);
            }
            // head MFMA: D[o][s] -> lane (quad0, s) regs 0..3
            f32x4 tv = mfma16(hda1, h1f, mfma16(hda0, h0, zero));
            if (lane < 16) stage[Mti * 16 + ms] = tv;
        }
        // batched epilogue: each lane finishes one of the 64 staged samples
        {
            f32x4 tq = stage[lane];
            int m2 = Mtb * 64 + lane;
            float sg = fmaxf(tq[0], 0.0f) + log1pf(__expf(-fabsf(tq[0])));
            float rr = sigmoidf(tq[1] + base_r);
            float gg = sigmoidf(tq[2] + base_g);
            float bb = sigmoidf(tq[3] + base_b);
            if (COARSE) {
                R.sgc[m2] = sg;
                R.rgbc[m2][0] = rr; R.rgbc[m2][1] = gg; R.rgbc[m2][2] = bb;
            } else {
                R.sgf[m2] = sg;
                R.rgbf[m2][0] = rr; R.rgbf[m2][1] = gg; R.rgbf[m2][2] = bb;
            }
        }
    }
}

__global__ __launch_bounds__(256)
void nerf_kernel(const float* __restrict__ rays_o, const float* __restrict__ rays_d,
                 const float* __restrict__ W1, const float* __restrict__ b1,
                 const float* __restrict__ W2, const float* __restrict__ b2,
                 const float* __restrict__ Wsig, const float* __restrict__ Wrgb,
                 const float* __restrict__ brgb,
                 float* __restrict__ out_depth, float* __restrict__ out_img,
                 int nRays)
{
    __shared__ RayLds rl[4];

    const int tid  = threadIdx.x;
    const int lane = tid & 63;
    const int wv   = tid >> 6;
    const int ms   = lane & 15;
    const int quad = lane >> 4;

    // --- W1 as 4 MFMA A-fragments (permuted units; only quad0 k=0..3 nonzero,
    //     b1 folded in at k=3 since P[3]=1) ---
    f16x8 w1a[4];
#pragma unroll
    for (int nt = 0; nt < 4; ++nt) {
        f16x8 t;
#pragma unroll
        for (int j = 0; j < 8; ++j) t[j] = (f16)0.f;
        if (quad == 0) {
            int u = 32 * (nt >> 1) + 8 * (ms >> 2) + 4 * (nt & 1) + (ms & 3);
            t[0] = (f16)W1[u];
            t[1] = (f16)W1[64 + u];
            t[2] = (f16)W1[128 + u];
            t[3] = (f16)b1[u];
        }
        w1a[nt] = t;
    }

    // --- W2 as 8 MFMA fragments with PERMUTED unit columns (byte-identical
    //     to verified R13: k-row logical index collapses to quad*8+j) ---
    const int colbase = 8 * (ms >> 2) + (ms & 3);
    f16x8 b00, b01, b10, b11, b20, b21, b30, b31;
#pragma unroll
    for (int j = 0; j < 8; ++j) {
        int k0 = (quad * 8 + j) * 64;
        int k1 = (32 + quad * 8 + j) * 64;
        b00[j] = (f16)W2[k0 + colbase];      b01[j] = (f16)W2[k1 + colbase];
        b10[j] = (f16)W2[k0 + colbase + 4];  b11[j] = (f16)W2[k1 + colbase + 4];
        b20[j] = (f16)W2[k0 + colbase + 32]; b21[j] = (f16)W2[k1 + colbase + 32];
        b30[j] = (f16)W2[k0 + colbase + 36]; b31[j] = (f16)W2[k1 + colbase + 36];
    }
    // b2 as C-operand vectors, same permutation
    f32x4 b2q0, b2q1, b2q2, b2q3;
#pragma unroll
    for (int r = 0; r < 4; ++r) {
        b2q0[r] = b2[8 * quad + r];
        b2q1[r] = b2[8 * quad + 4 + r];
        b2q2[r] = b2[32 + 8 * quad + r];
        b2q3[r] = b2[32 + 8 * quad + 4 + r];
    }
    // head weight A-fragments (rows 4..15 garbage-but-unread)
    f16x8 hda0, hda1;
    {
        int msel = ms & 3;
#pragma unroll
        for (int j = 0; j < 8; ++j) {
            int u0 = quad * 8 + j, u1 = 32 + quad * 8 + j;
            float w0 = (msel == 0) ? Wsig[u0] : Wrgb[u0 * 3 + msel - 1];
            float w1 = (msel == 0) ? Wsig[u1] : Wrgb[u1 * 3 + msel - 1];
            hda0[j] = (f16)w0;
            hda1[j] = (f16)w1;
        }
    }

    int ray = blockIdx.x * 4 + wv;
    bool valid = ray < nRays;
    int rayc = valid ? ray : (nRays - 1);
    RayLds& R = rl[wv];

    const float ox = rays_o[rayc * 3 + 0], oy = rays_o[rayc * 3 + 1], oz = rays_o[rayc * 3 + 2];
    const float dx = rays_d[rayc * 3 + 0], dy = rays_d[rayc * 3 + 1], dzv = rays_d[rayc * 3 + 2];

    // --- near/far vs cube [-2,2]^3 ---
    float t0x = (-BOUNDF - ox) / (dx + 1e-15f), t1x = (BOUNDF - ox) / (dx + 1e-15f);
    float t0y = (-BOUNDF - oy) / (dy + 1e-15f), t1y = (BOUNDF - oy) / (dy + 1e-15f);
    float t0z = (-BOUNDF - oz) / (dzv + 1e-15f), t1z = (BOUNDF - oz) / (dzv + 1e-15f);
    float nearv = fmaxf(fminf(t0x, t1x), fmaxf(fminf(t0y, t1y), fminf(t0z, t1z)));
    float farv  = fminf(fmaxf(t0x, t1x), fminf(fmaxf(t0y, t1y), fmaxf(t0z, t1z)));
    if (farv < nearv) { nearv = 1e9f; farv = 1e9f; }
    nearv = fmaxf(nearv, 0.05f);
    const float span = farv - nearv;
    const float dzc = span * (1.0f / 127.0f);
    const float sample_dist = span * (1.0f / 128.0f);

    const float base_r = brgb[0] + dx * Wrgb[64 * 3 + 0] + dy * Wrgb[65 * 3 + 0] + dzv * Wrgb[66 * 3 + 0];
    const float base_g = brgb[1] + dx * Wrgb[64 * 3 + 1] + dy * Wrgb[65 * 3 + 1] + dzv * Wrgb[66 * 3 + 1];
    const float base_b = brgb[2] + dx * Wrgb[64 * 3 + 2] + dy * Wrgb[65 * 3 + 2] + dzv * Wrgb[66 * 3 + 2];

    const int s0 = lane, s1 = lane + 64;

    // z_vals
    R.zc[s0] = fmaf(span, (float)s0 * (1.0f / 127.0f), nearv);
    R.zc[s1] = fmaf(span, (float)s1 * (1.0f / 127.0f), nearv);

    // --- coarse field pass (triple MFMA) ---
    field_pass<true>(R, w1a[0], w1a[1], w1a[2], w1a[3],
                     b00, b01, b10, b11, b20, b21, b30, b31,
                     hda0, hda1, b2q0, b2q1, b2q2, b2q3,
                     ox, oy, oz, dx, dy, dzv, nearv, span, base_r, base_g, base_b, lane);

    // --- coarse alphas ---
    {
        float zA = R.zc[s0], zB = R.zc[s1];
        float dA = R.zc[s0 + 1] - zA;
        float dB = (s1 < 127) ? (R.zc[s1 + 1] - zB) : sample_dist;
        R.scr[s0] = 1.0f - __expf(-dA * R.sgc[s0]);
        R.scr[s1] = 1.0f - __expf(-dB * R.sgc[s1]);
    }

    // --- wave-parallel cumprod: weights for elements 2l, 2l+1 ---
    {
        float aa = R.scr[2 * lane], ab = R.scr[2 * lane + 1];
        float ma = 1.0f - aa + 1e-15f, mb = 1.0f - ab + 1e-15f;
        float p = scan_incl_mul(ma * mb, lane);
        float T0 = __shfl_up(p, 1, 64);
        if (lane == 0) T0 = 1.0f;
        R.scr[2 * lane]     = aa * T0;
        R.scr[2 * lane + 1] = ab * (T0 * ma);
    }

    // --- wave-parallel CDF over pdf[m]=w[1+m]+1e-5, m=0..125 ---
    {
        float pA = 0.f, pB = 0.f;
        if (lane < 63) {
            pA = R.scr[2 * lane + 1] + 1e-5f;
            pB = R.scr[2 * lane + 2] + 1e-5f;
        }
        float S = scan_incl_add(pA + pB, lane);
        float total = __shfl(S, 63, 64);
        float sexcl = __shfl_up(S, 1, 64);
        if (lane == 0) sexcl = 0.f;
        float inv = 1.0f / total;
        if (lane == 63) {
            R.cdf[0] = 0.0f;
        } else {
            R.cdf[1 + 2 * lane] = (sexcl + pA) * inv;
            R.cdf[2 + 2 * lane] = (sexcl + pA + pB) * inv;
        }
    }

    // --- inverse-CDF sampling ---
#pragma unroll
    for (int bt = 0; bt < 2; ++bt) {
        int i = bt * 64 + lane;
        float u = (float)(2 * i + 1) * (1.0f / 256.0f);
        int lo = 0, hi = 127;
        while (lo < hi) { int mid = (lo + hi) >> 1; if (R.cdf[mid] <= u) lo = mid + 1; else hi = mid; }
        int below = max(lo - 1, 0), above = min(lo, 126);
        float cb = R.cdf[below], ca = R.cdf[above];
        float binb = fmaf(dzc, (float)below + 0.5f, nearv);
        float bina = fmaf(dzc, (float)above + 0.5f, nearv);
        float denom = ca - cb;
        if (denom < 1e-5f) denom = 1.0f;
        float t = (u - cb) / denom;
        R.zf[i] = fmaf(t, bina - binb, binb);
    }

    // --- fine field pass (triple MFMA; cdf/scr are free to reuse as stage) ---
    field_pass<false>(R, w1a[0], w1a[1], w1a[2], w1a[3],
                      b00, b01, b10, b11, b20, b21, b30, b31,
                      hda0, hda1, b2q0, b2q1, b2q2, b2q3,
                      ox, oy, oz, dx, dy, dzv, nearv, span, base_r, base_g, base_b, lane);

    // --- stable merge of two sorted length-128 lists ---
#pragma unroll
    for (int bt = 0; bt < 2; ++bt) {
        int k = bt * 64 + lane;
        float v = R.zc[k];
        int lo = 0, hi = 128;
        while (lo < hi) { int mid = (lo + hi) >> 1; if (R.zf[mid] < v) lo = mid + 1; else hi = mid; }
        R.perm[k + lo] = (unsigned short)k;
        float vf = R.zf[k];
        lo = 0; hi = 128;
        while (lo < hi) { int mid = (lo + hi) >> 1; if (R.zc[mid] <= vf) lo = mid + 1; else hi = mid; }
        R.perm[k + lo] = (unsigned short)(128 + k);
    }

    // --- merged composite ---
    {
        int sb = 4 * lane;
        int idxk[4]; float zk[4], sgk[4];
#pragma unroll
        for (int k = 0; k < 4; ++k) {
            int idx = R.perm[sb + k];
            idxk[k] = idx;
            zk[k]  = (idx < 128) ? R.zc[idx]  : R.zf[idx - 128];
            sgk[k] = (idx < 128) ? R.sgc[idx] : R.sgf[idx - 128];
        }
        float znext = __shfl_down(zk[0], 1, 64);
        float d0 = zk[1] - zk[0];
        float d1 = zk[2] - zk[1];
        float d2 = zk[3] - zk[2];
        float d3 = (lane < 63) ? (znext - zk[3]) : sample_dist;
        float a0 = 1.0f - __expf(-d0 * sgk[0]);
        float a1 = 1.0f - __expf(-d1 * sgk[1]);
        float a2 = 1.0f - __expf(-d2 * sgk[2]);
        float a3 = 1.0f - __expf(-d3 * sgk[3]);
        float m0 = 1.0f - a0 + 1e-15f, m1 = 1.0f - a1 + 1e-15f;
        float m2 = 1.0f - a2 + 1e-15f, m3 = 1.0f - a3 + 1e-15f;
        float p = scan_incl_mul((m0 * m1) * (m2 * m3), lane);
        float T = __shfl_up(p, 1, 64);
        if (lane == 0) T = 1.0f;

        const float invspan = 1.0f / span;
        float dacc = 0.f, racc = 0.f, gacc = 0.f, bacc = 0.f, wacc = 0.f;
        float aarr[4] = {a0, a1, a2, a3};
        float marr[4] = {m0, m1, m2, m3};
#pragma unroll
        for (int k = 0; k < 4; ++k) {
            float w = aarr[k] * T;
            float ozv = (zk[k] - nearv) * invspan;
            ozv = (ozv < 0.0f) ? 0.0f : ((ozv > 1.0f) ? 1.0f : ozv);
            dacc = fmaf(w, ozv, dacc);
            const float* rgb = (idxk[k] < 128) ? R.rgbc[idxk[k]] : R.rgbf[idxk[k] - 128];
            racc = fmaf(w, rgb[0], racc);
            gacc = fmaf(w, rgb[1], gacc);
            bacc = fmaf(w, rgb[2], bacc);
            wacc += w;
            T *= marr[k];
        }
#pragma unroll
        for (int off = 32; off; off >>= 1) {
            dacc += __shfl_xor(dacc, off);
            racc += __shfl_xor(racc, off);
            gacc += __shfl_xor(gacc, off);
            bacc += __shfl_xor(bacc, off);
            wacc += __shfl_xor(wacc, off);
        }
        if (lane == 0 && valid) {
            out_depth[ray] = dacc;
            float bg = 1.0f - wacc;
            out_img[ray * 3 + 0] = racc + bg;
            out_img[ray * 3 + 1] = gacc + bg;
            out_img[ray * 3 + 2] = bacc + bg;
        }
    }
}

extern "C" void kernel_launch(void* const* d_in, const int* in_sizes, int n_in,
                              void* d_out, int out_size, void* d_ws, size_t ws_size,
                              hipStream_t stream) {
    const float* rays_o = (const float*)d_in[0];
    const float* rays_d = (const float*)d_in[1];
    const float* W1   = (const float*)d_in[2];
    const float* b1   = (const float*)d_in[3];
    const float* W2   = (const float*)d_in[4];
    const float* b2   = (const float*)d_in[5];
    const float* Wsig = (const float*)d_in[6];
    const float* Wrgb = (const float*)d_in[7];
    const float* brgb = (const float*)d_in[8];

    int N = in_sizes[0] / 3;          // 4096 rays
    float* out = (float*)d_out;
    float* out_depth = out;           // [N]
    float* out_img   = out + N;       // [N,3]

    int blocks = (N + 3) / 4;
    nerf_kernel<<<dim3(blocks), dim3(256), 0, stream>>>(
        rays_o, rays_d, W1, b1, W2, b2, Wsig, Wrgb, brgb,
        out_depth, out_img, N);
}

// Round 16
// 104.738 us; speedup vs baseline: 3.1849x; 1.0173x over previous
//
#include <hip/hip_runtime.h>
#include <math.h>

// NeRF renderer: 4096 rays, 128+128 samples, tiny MLP field.
// One wave per ray. ALL THREE layers run on the matrix pipe:
//   L1: mfma(W1_frag, P_frag)  -> h1 (K=4 zero-padded to 32; b1 via P[3]=1)
//   L2: mfma(W2_frag, h1_frag) -> h2 (b2 in the C operand)
//   HD: mfma(HD_frag, h2_frag) -> {sigma_pre, c0, c1, c2} per sample
// Unit-permutation trick (verified R13/R14): each MFMA's D-physical layout IS
// the next MFMA's B-fragment layout — zero cross-lane movement.
// R16 (=R15 fixed): Mti unroll-2 (two independent MFMA chains in flight to
// fill the ~30% latency stall seen in R14's 57% VALUBusy + 13% MfmaUtil),
// packed v_cvt_pkrtz f32->f16x2 conversions (bit_cast: the builtin returns
// __fp16x2, not _Float16x2), fast __logf/rcp epilogue.
//
// Spill discipline (R2..R8): no __launch_bounds__ min-waves arg. No dynamic
// indexing of private arrays (unions below use constant indices only).
// hbm_bytes <2 MB == clean; VGPR must stay <=128 (4 waves/SIMD bin).

#define BOUNDF 2.0f

typedef _Float16 f16;
typedef f16 f16x2 __attribute__((ext_vector_type(2)));
typedef f16 f16x8 __attribute__((ext_vector_type(8)));
typedef float f32x4 __attribute__((ext_vector_type(4)));

union U16 { f16x8 v8; f16x2 v2[4]; };

struct RayLds {
    float zc[128];
    float zf[128];
    float sgc[128];
    float sgf[128];
    float rgbc[128][3];
    float rgbf[128][3];
    float cdf[128];       // cdf+scr double as the 256-float epilogue stage
    float scr[128];       //   (must stay adjacent & 16B-aligned)
    unsigned short perm[256];
};

__device__ __forceinline__ f32x4 mfma16(f16x8 a, f16x8 b, f32x4 c) {
    return __builtin_amdgcn_mfma_f32_16x16x32_f16(a, b, c, 0, 0, 0);
}

__device__ __forceinline__ f16x2 pkrtz(float a, float b) {
    return __builtin_bit_cast(f16x2, __builtin_amdgcn_cvt_pkrtz(a, b));
}

__device__ __forceinline__ f16x2 relu_cvt(float a, float b) {
    return pkrtz(fmaxf(a, 0.0f), fmaxf(b, 0.0f));
}

__device__ __forceinline__ float scan_incl_mul(float p, int lane) {
#pragma unroll
    for (int off = 1; off < 64; off <<= 1) {
        float t = __shfl_up(p, off, 64);
        if (lane >= off) p *= t;
    }
    return p;
}

__device__ __forceinline__ float scan_incl_add(float p, int lane) {
#pragma unroll
    for (int off = 1; off < 64; off <<= 1) {
        float t = __shfl_up(p, off, 64);
        if (lane >= off) p += t;
    }
    return p;
}

// One field pass (128 samples) for one ray/wave, via triple MFMA.
template<bool COARSE>
__device__ __forceinline__ void field_pass(
    RayLds& R,
    f16x8 w1a0, f16x8 w1a1, f16x8 w1a2, f16x8 w1a3,
    f16x8 b00, f16x8 b01, f16x8 b10, f16x8 b11,
    f16x8 b20, f16x8 b21, f16x8 b30, f16x8 b31,
    f16x8 hda0, f16x8 hda1,
    f32x4 b2q0, f32x4 b2q1, f32x4 b2q2, f32x4 b2q3,
    float ox, float oy, float oz, float dx, float dy, float dzv,
    float nearv, float span, float base_r, float base_g, float base_b, int lane)
{
    const int ms = lane & 15;          // sample-within-tile
    f32x4* stage = (f32x4*)(&R.cdf[0]);   // 256 floats: cdf+scr (idle here)
    const f32x4 zero = {0.f, 0.f, 0.f, 0.f};
#pragma unroll 1
    for (int Mtb = 0; Mtb < 2; ++Mtb) {
#pragma unroll 2
        for (int Mti = 0; Mti < 4; ++Mti) {
            int m = Mtb * 64 + Mti * 16 + ms;
            float z = COARSE ? fmaf(span, (float)m * (1.0f / 127.0f), nearv) : R.zf[m];
            float px = fminf(fmaxf(fmaf(dx, z, ox), -BOUNDF), BOUNDF);
            float py = fminf(fmaxf(fmaf(dy, z, oy), -BOUNDF), BOUNDF);
            float pz = fminf(fmaxf(fmaf(dzv, z, oz), -BOUNDF), BOUNDF);

            // P B-fragment (packed cvt): only k=0..3 on quad0 matter
            U16 up;
            up.v2[0] = pkrtz(px, py);
            up.v2[1] = pkrtz(pz, 1.0f);
            up.v2[2] = f16x2{(f16)0.f, (f16)0.f};
            up.v2[3] = f16x2{(f16)0.f, (f16)0.f};
            f16x8 pf = up.v8;

            // layer-1 MFMA: hacc_nt[r] = h1pre[phys (nt,quad,r)][ms]
            f32x4 hacc0 = mfma16(w1a0, pf, zero);
            f32x4 hacc1 = mfma16(w1a1, pf, zero);
            f32x4 hacc2 = mfma16(w1a2, pf, zero);
            f32x4 hacc3 = mfma16(w1a3, pf, zero);

            // relu + packed cvt: physical layout IS the L2 B-fragment layout
            U16 u0, u1;
            u0.v2[0] = relu_cvt(hacc0[0], hacc0[1]);
            u0.v2[1] = relu_cvt(hacc0[2], hacc0[3]);
            u0.v2[2] = relu_cvt(hacc1[0], hacc1[1]);
            u0.v2[3] = relu_cvt(hacc1[2], hacc1[3]);
            u1.v2[0] = relu_cvt(hacc2[0], hacc2[1]);
            u1.v2[1] = relu_cvt(hacc2[2], hacc2[3]);
            u1.v2[2] = relu_cvt(hacc3[0], hacc3[1]);
            u1.v2[3] = relu_cvt(hacc3[2], hacc3[3]);
            f16x8 hf0 = u0.v8, hf1 = u1.v8;

            // layer-2 MFMA (bias in C): acc_nt[r] = h2[phys (nt,quad,r)][ms]
            f32x4 acc0 = mfma16(b01, hf1, mfma16(b00, hf0, b2q0));
            f32x4 acc1 = mfma16(b11, hf1, mfma16(b10, hf0, b2q1));
            f32x4 acc2 = mfma16(b21, hf1, mfma16(b20, hf0, b2q2));
            f32x4 acc3 = mfma16(b31, hf1, mfma16(b30, hf0, b2q3));

            // relu + packed cvt: physical layout IS the head B-fragment layout
            U16 v0, v1;
            v0.v2[0] = relu_cvt(acc0[0], acc0[1]);
            v0.v2[1] = relu_cvt(acc0[2], acc0[3]);
            v0.v2[2] = relu_cvt(acc1[0], acc1[1]);
            v0.v2[3] = relu_cvt(acc1[2], acc1[3]);
            v1.v2[0] = relu_cvt(acc2[0], acc2[1]);
            v1.v2[1] = relu_cvt(acc2[2], acc2[3]);
            v1.v2[2] = relu_cvt(acc3[0], acc3[1]);
            v1.v2[3] = relu_cvt(acc3[2], acc3[3]);
            f16x8 h0 = v0.v8, h1f = v1.v8;

            // head MFMA: D[o][s] -> lane (quad0, s) regs 0..3
            f32x4 tv = mfma16(hda1, h1f, mfma16(hda0, h0, zero));
            if (lane < 16) stage[Mti * 16 + ms] = tv;
        }
        // batched epilogue: each lane finishes one of the 64 staged samples
        {
            f32x4 tq = stage[lane];
            int m2 = Mtb * 64 + lane;
            float e  = __expf(-fabsf(tq[0]));
            float sg = fmaxf(tq[0], 0.0f) + __logf(1.0f + e);   // stable softplus
            float rr = __builtin_amdgcn_rcpf(1.0f + __expf(-(tq[1] + base_r)));
            float gg = __builtin_amdgcn_rcpf(1.0f + __expf(-(tq[2] + base_g)));
            float bb = __builtin_amdgcn_rcpf(1.0f + __expf(-(tq[3] + base_b)));
            if (COARSE) {
                R.sgc[m2] = sg;
                R.rgbc[m2][0] = rr; R.rgbc[m2][1] = gg; R.rgbc[m2][2] = bb;
            } else {
                R.sgf[m2] = sg;
                R.rgbf[m2][0] = rr; R.rgbf[m2][1] = gg; R.rgbf[m2][2] = bb;
            }
        }
    }
}

__global__ __launch_bounds__(256)
void nerf_kernel(const float* __restrict__ rays_o, const float* __restrict__ rays_d,
                 const float* __restrict__ W1, const float* __restrict__ b1,
                 const float* __restrict__ W2, const float* __restrict__ b2,
                 const float* __restrict__ Wsig, const float* __restrict__ Wrgb,
                 const float* __restrict__ brgb,
                 float* __restrict__ out_depth, float* __restrict__ out_img,
                 int nRays)
{
    __shared__ RayLds rl[4];

    const int tid  = threadIdx.x;
    const int lane = tid & 63;
    const int wv   = tid >> 6;
    const int ms   = lane & 15;
    const int quad = lane >> 4;

    // --- W1 as 4 MFMA A-fragments (permuted units; only quad0 k=0..3 nonzero,
    //     b1 folded in at k=3 since P[3]=1) ---
    f16x8 w1a[4];
#pragma unroll
    for (int nt = 0; nt < 4; ++nt) {
        f16x8 t;
#pragma unroll
        for (int j = 0; j < 8; ++j) t[j] = (f16)0.f;
        if (quad == 0) {
            int u = 32 * (nt >> 1) + 8 * (ms >> 2) + 4 * (nt & 1) + (ms & 3);
            t[0] = (f16)W1[u];
            t[1] = (f16)W1[64 + u];
            t[2] = (f16)W1[128 + u];
            t[3] = (f16)b1[u];
        }
        w1a[nt] = t;
    }

    // --- W2 as 8 MFMA fragments with PERMUTED unit columns (byte-identical
    //     to verified R13/R14) ---
    const int colbase = 8 * (ms >> 2) + (ms & 3);
    f16x8 b00, b01, b10, b11, b20, b21, b30, b31;
#pragma unroll
    for (int j = 0; j < 8; ++j) {
        int k0 = (quad * 8 + j) * 64;
        int k1 = (32 + quad * 8 + j) * 64;
        b00[j] = (f16)W2[k0 + colbase];      b01[j] = (f16)W2[k1 + colbase];
        b10[j] = (f16)W2[k0 + colbase + 4];  b11[j] = (f16)W2[k1 + colbase + 4];
        b20[j] = (f16)W2[k0 + colbase + 32]; b21[j] = (f16)W2[k1 + colbase + 32];
        b30[j] = (f16)W2[k0 + colbase + 36]; b31[j] = (f16)W2[k1 + colbase + 36];
    }
    // b2 as C-operand vectors, same permutation
    f32x4 b2q0, b2q1, b2q2, b2q3;
#pragma unroll
    for (int r = 0; r < 4; ++r) {
        b2q0[r] = b2[8 * quad + r];
        b2q1[r] = b2[8 * quad + 4 + r];
        b2q2[r] = b2[32 + 8 * quad + r];
        b2q3[r] = b2[32 + 8 * quad + 4 + r];
    }
    // head weight A-fragments (rows 4..15 garbage-but-unread)
    f16x8 hda0, hda1;
    {
        int msel = ms & 3;
#pragma unroll
        for (int j = 0; j < 8; ++j) {
            int u0 = quad * 8 + j, u1 = 32 + quad * 8 + j;
            float w0 = (msel == 0) ? Wsig[u0] : Wrgb[u0 * 3 + msel - 1];
            float w1 = (msel == 0) ? Wsig[u1] : Wrgb[u1 * 3 + msel - 1];
            hda0[j] = (f16)w0;
            hda1[j] = (f16)w1;
        }
    }

    int ray = blockIdx.x * 4 + wv;
    bool valid = ray < nRays;
    int rayc = valid ? ray : (nRays - 1);
    RayLds& R = rl[wv];

    const float ox = rays_o[rayc * 3 + 0], oy = rays_o[rayc * 3 + 1], oz = rays_o[rayc * 3 + 2];
    const float dx = rays_d[rayc * 3 + 0], dy = rays_d[rayc * 3 + 1], dzv = rays_d[rayc * 3 + 2];

    // --- near/far vs cube [-2,2]^3 ---
    float t0x = (-BOUNDF - ox) / (dx + 1e-15f), t1x = (BOUNDF - ox) / (dx + 1e-15f);
    float t0y = (-BOUNDF - oy) / (dy + 1e-15f), t1y = (BOUNDF - oy) / (dy + 1e-15f);
    float t0z = (-BOUNDF - oz) / (dzv + 1e-15f), t1z = (BOUNDF - oz) / (dzv + 1e-15f);
    float nearv = fmaxf(fminf(t0x, t1x), fmaxf(fminf(t0y, t1y), fminf(t0z, t1z)));
    float farv  = fminf(fmaxf(t0x, t1x), fminf(fmaxf(t0y, t1y), fmaxf(t0z, t1z)));
    if (farv < nearv) { nearv = 1e9f; farv = 1e9f; }
    nearv = fmaxf(nearv, 0.05f);
    const float span = farv - nearv;
    const float dzc = span * (1.0f / 127.0f);
    const float sample_dist = span * (1.0f / 128.0f);

    const float base_r = brgb[0] + dx * Wrgb[64 * 3 + 0] + dy * Wrgb[65 * 3 + 0] + dzv * Wrgb[66 * 3 + 0];
    const float base_g = brgb[1] + dx * Wrgb[64 * 3 + 1] + dy * Wrgb[65 * 3 + 1] + dzv * Wrgb[66 * 3 + 1];
    const float base_b = brgb[2] + dx * Wrgb[64 * 3 + 2] + dy * Wrgb[65 * 3 + 2] + dzv * Wrgb[66 * 3 + 2];

    const int s0 = lane, s1 = lane + 64;

    // z_vals
    R.zc[s0] = fmaf(span, (float)s0 * (1.0f / 127.0f), nearv);
    R.zc[s1] = fmaf(span, (float)s1 * (1.0f / 127.0f), nearv);

    // --- coarse field pass (triple MFMA) ---
    field_pass<true>(R, w1a[0], w1a[1], w1a[2], w1a[3],
                     b00, b01, b10, b11, b20, b21, b30, b31,
                     hda0, hda1, b2q0, b2q1, b2q2, b2q3,
                     ox, oy, oz, dx, dy, dzv, nearv, span, base_r, base_g, base_b, lane);

    // --- coarse alphas ---
    {
        float zA = R.zc[s0], zB = R.zc[s1];
        float dA = R.zc[s0 + 1] - zA;
        float dB = (s1 < 127) ? (R.zc[s1 + 1] - zB) : sample_dist;
        R.scr[s0] = 1.0f - __expf(-dA * R.sgc[s0]);
        R.scr[s1] = 1.0f - __expf(-dB * R.sgc[s1]);
    }

    // --- wave-parallel cumprod: weights for elements 2l, 2l+1 ---
    {
        float aa = R.scr[2 * lane], ab = R.scr[2 * lane + 1];
        float ma = 1.0f - aa + 1e-15f, mb = 1.0f - ab + 1e-15f;
        float p = scan_incl_mul(ma * mb, lane);
        float T0 = __shfl_up(p, 1, 64);
        if (lane == 0) T0 = 1.0f;
        R.scr[2 * lane]     = aa * T0;
        R.scr[2 * lane + 1] = ab * (T0 * ma);
    }

    // --- wave-parallel CDF over pdf[m]=w[1+m]+1e-5, m=0..125 ---
    {
        float pA = 0.f, pB = 0.f;
        if (lane < 63) {
            pA = R.scr[2 * lane + 1] + 1e-5f;
            pB = R.scr[2 * lane + 2] + 1e-5f;
        }
        float S = scan_incl_add(pA + pB, lane);
        float total = __shfl(S, 63, 64);
        float sexcl = __shfl_up(S, 1, 64);
        if (lane == 0) sexcl = 0.f;
        float inv = 1.0f / total;
        if (lane == 63) {
            R.cdf[0] = 0.0f;
        } else {
            R.cdf[1 + 2 * lane] = (sexcl + pA) * inv;
            R.cdf[2 + 2 * lane] = (sexcl + pA + pB) * inv;
        }
    }

    // --- inverse-CDF sampling ---
#pragma unroll
    for (int bt = 0; bt < 2; ++bt) {
        int i = bt * 64 + lane;
        float u = (float)(2 * i + 1) * (1.0f / 256.0f);
        int lo = 0, hi = 127;
        while (lo < hi) { int mid = (lo + hi) >> 1; if (R.cdf[mid] <= u) lo = mid + 1; else hi = mid; }
        int below = max(lo - 1, 0), above = min(lo, 126);
        float cb = R.cdf[below], ca = R.cdf[above];
        float binb = fmaf(dzc, (float)below + 0.5f, nearv);
        float bina = fmaf(dzc, (float)above + 0.5f, nearv);
        float denom = ca - cb;
        if (denom < 1e-5f) denom = 1.0f;
        float t = (u - cb) / denom;
        R.zf[i] = fmaf(t, bina - binb, binb);
    }

    // --- fine field pass (triple MFMA; cdf/scr free to reuse as stage) ---
    field_pass<false>(R, w1a[0], w1a[1], w1a[2], w1a[3],
                      b00, b01, b10, b11, b20, b21, b30, b31,
                      hda0, hda1, b2q0, b2q1, b2q2, b2q3,
                      ox, oy, oz, dx, dy, dzv, nearv, span, base_r, base_g, base_b, lane);

    // --- stable merge of two sorted length-128 lists ---
#pragma unroll
    for (int bt = 0; bt < 2; ++bt) {
        int k = bt * 64 + lane;
        float v = R.zc[k];
        int lo = 0, hi = 128;
        while (lo < hi) { int mid = (lo + hi) >> 1; if (R.zf[mid] < v) lo = mid + 1; else hi = mid; }
        R.perm[k + lo] = (unsigned short)k;
        float vf = R.zf[k];
        lo = 0; hi = 128;
        while (lo < hi) { int mid = (lo + hi) >> 1; if (R.zc[mid] <= vf) lo = mid + 1; else hi = mid; }
        R.perm[k + lo] = (unsigned short)(128 + k);
    }

    // --- merged composite ---
    {
        int sb = 4 * lane;
        int idxk[4]; float zk[4], sgk[4];
#pragma unroll
        for (int k = 0; k < 4; ++k) {
            int idx = R.perm[sb + k];
            idxk[k] = idx;
            zk[k]  = (idx < 128) ? R.zc[idx]  : R.zf[idx - 128];
            sgk[k] = (idx < 128) ? R.sgc[idx] : R.sgf[idx - 128];
        }
        float znext = __shfl_down(zk[0], 1, 64);
        float d0 = zk[1] - zk[0];
        float d1 = zk[2] - zk[1];
        float d2 = zk[3] - zk[2];
        float d3 = (lane < 63) ? (znext - zk[3]) : sample_dist;
        float a0 = 1.0f - __expf(-d0 * sgk[0]);
        float a1 = 1.0f - __expf(-d1 * sgk[1]);
        float a2 = 1.0f - __expf(-d2 * sgk[2]);
        float a3 = 1.0f - __expf(-d3 * sgk[3]);
        float m0 = 1.0f - a0 + 1e-15f, m1 = 1.0f - a1 + 1e-15f;
        float m2 = 1.0f - a2 + 1e-15f, m3 = 1.0f - a3 + 1e-15f;
        float p = scan_incl_mul((m0 * m1) * (m2 * m3), lane);
        float T = __shfl_up(p, 1, 64);
        if (lane == 0) T = 1.0f;

        const float invspan = 1.0f / span;
        float dacc = 0.f, racc = 0.f, gacc = 0.f, bacc = 0.f, wacc = 0.f;
        float aarr[4] = {a0, a1, a2, a3};
        float marr[4] = {m0, m1, m2, m3};
#pragma unroll
        for (int k = 0; k < 4; ++k) {
            float w = aarr[k] * T;
            float ozv = (zk[k] - nearv) * invspan;
            ozv = (ozv < 0.0f) ? 0.0f : ((ozv > 1.0f) ? 1.0f : ozv);
            dacc = fmaf(w, ozv, dacc);
            const float* rgb = (idxk[k] < 128) ? R.rgbc[idxk[k]] : R.rgbf[idxk[k] - 128];
            racc = fmaf(w, rgb[0], racc);
            gacc = fmaf(w, rgb[1], gacc);
            bacc = fmaf(w, rgb[2], bacc);
            wacc += w;
            T *= marr[k];
        }
#pragma unroll
        for (int off = 32; off; off >>= 1) {
            dacc += __shfl_xor(dacc, off);
            racc += __shfl_xor(racc, off);
            gacc += __shfl_xor(gacc, off);
            bacc += __shfl_xor(bacc, off);
            wacc += __shfl_xor(wacc, off);
        }
        if (lane == 0 && valid) {
            out_depth[ray] = dacc;
            float bg = 1.0f - wacc;
            out_img[ray * 3 + 0] = racc + bg;
            out_img[ray * 3 + 1] = gacc + bg;
            out_img[ray * 3 + 2] = bacc + bg;
        }
    }
}

extern "C" void kernel_launch(void* const* d_in, const int* in_sizes, int n_in,
                              void* d_out, int out_size, void* d_ws, size_t ws_size,
                              hipStream_t stream) {
    const float* rays_o = (const float*)d_in[0];
    const float* rays_d = (const float*)d_in[1];
    const float* W1   = (const float*)d_in[2];
    const float* b1   = (const float*)d_in[3];
    const float* W2   = (const float*)d_in[4];
    const float* b2   = (const float*)d_in[5];
    const float* Wsig = (const float*)d_in[6];
    const float* Wrgb = (const float*)d_in[7];
    const float* brgb = (const float*)d_in[8];

    int N = in_sizes[0] / 3;          // 4096 rays
    float* out = (float*)d_out;
    float* out_depth = out;           // [N]
    float* out_img   = out + N;       // [N,3]

    int blocks = (N + 3) / 4;
    nerf_kernel<<<dim3(blocks), dim3(256), 0, stream>>>(
        rays_o, rays_d, W1, b1, W2, b2, Wsig, Wrgb, brgb,
        out_depth, out_img, N);
}